// Round 6
// baseline (472.767 us; speedup 1.0000x reference)
//
#include <hip/hip_runtime.h>
#include <math.h>
#include <stdint.h>

#define L_  1024
#define B_  2
#define D_  1024
#define H_  16
#define DH_ 64
#define M_  1024
#define T_  2048
#define SCALE_ 0.125f

typedef unsigned short ushort;
typedef short bf16x8 __attribute__((ext_vector_type(8)));
typedef float f32x4 __attribute__((ext_vector_type(4)));
typedef unsigned short u16x4v __attribute__((ext_vector_type(4)));
typedef unsigned short u16x8v __attribute__((ext_vector_type(8)));

#define MFMA16(a,b,c) __builtin_amdgcn_mfma_f32_16x16x32_bf16(a,b,c,0,0,0)

static __device__ __forceinline__ ushort f2bf(float x) {
    uint32_t u = __float_as_uint(x);
    uint32_t r = (u + 0x7FFFu + ((u >> 16) & 1u)) >> 16;
    return (ushort)r;
}
static __device__ __forceinline__ float bf2f(ushort h) {
    return __uint_as_float(((uint32_t)h) << 16);
}
// async global->LDS, 16B per lane; LDS dest = wave-uniform base + lane*16
static __device__ __forceinline__ void gl_lds16(const ushort* g, ushort* l) {
    __builtin_amdgcn_global_load_lds(
        (const __attribute__((address_space(1))) void*)g,
        (__attribute__((address_space(3))) void*)l, 16, 0, 0);
}

// ---------------------------------------------------------------------------
// fp32 -> bf16 convert
// ---------------------------------------------------------------------------
__global__ __launch_bounds__(256) void cvt_bf16(const float* __restrict__ src,
                                                ushort* __restrict__ dst, int n) {
    int i = (blockIdx.x * 256 + threadIdx.x) * 8;
    if (i >= n) return;
    float4 a = *(const float4*)(src + i);
    float4 b = *(const float4*)(src + i + 4);
    u16x8v o;
    o[0] = f2bf(a.x); o[1] = f2bf(a.y); o[2] = f2bf(a.z); o[3] = f2bf(a.w);
    o[4] = f2bf(b.x); o[5] = f2bf(b.y); o[6] = f2bf(b.z); o[7] = f2bf(b.w);
    *(u16x8v*)(dst + i) = o;
}

// ---------------------------------------------------------------------------
// fp32 [K][N] -> bf16 [N][K] transpose+convert. 32x32 tiles, 256 thr.
// ---------------------------------------------------------------------------
__global__ __launch_bounds__(256) void trans_cvt(const float* __restrict__ src,
                                                 ushort* __restrict__ dst,
                                                 int K, int N) {
    __shared__ float t[32][33];
    int k0 = blockIdx.x * 32, n0 = blockIdx.y * 32;
    int tid = threadIdx.x;
    int r = tid >> 3, c4 = (tid & 7) * 4;
    float4 v = *(const float4*)(src + (size_t)(k0 + r) * N + n0 + c4);
    t[r][c4 + 0] = v.x; t[r][c4 + 1] = v.y; t[r][c4 + 2] = v.z; t[r][c4 + 3] = v.w;
    __syncthreads();
    u16x4v o;
    o[0] = f2bf(t[c4 + 0][r]); o[1] = f2bf(t[c4 + 1][r]);
    o[2] = f2bf(t[c4 + 2][r]); o[3] = f2bf(t[c4 + 3][r]);
    *(u16x4v*)(dst + (size_t)(n0 + r) * K + k0 + c4) = o;
}

// ---------------------------------------------------------------------------
// 128x128-tile bf16 MFMA GEMM (m97 structure): C = A[M][1024] @ Wt[N][1024]^T
// BK=32, global_load_lds(16B) staging, 4 waves 2x2, each 64x64 via 4x4 MFMA.
// omode 0: q -> qu=(+bu), qv=(+bv), layout [bh][L][64]
// omode 1: kv -> n<1024: k row-major [bh][T][64]; else v TRANSPOSED [bh][64][T]
// omode 2: r -> [bh][T][64]
// omode 3: outF[m][n] = acc + resid  (fp32)
// ---------------------------------------------------------------------------
__global__ __launch_bounds__(256) void gemm128(
    const ushort* __restrict__ A, const ushort* __restrict__ Wt,
    int omode,
    const float* __restrict__ bu, const float* __restrict__ bv,
    ushort* __restrict__ outA, ushort* __restrict__ outB,
    const float* __restrict__ resid, float* __restrict__ outF)
{
    __shared__ ushort Al[128 * 32];   // row stride 32 ushorts (64 B), contiguous
    __shared__ ushort Bl[128 * 32];
    int tid = threadIdx.x;
    int wid = tid >> 6, lane = tid & 63, quad = lane >> 4, jl = lane & 15;
    int wr = wid >> 1, wc = wid & 1;
    int M0 = blockIdx.x * 128, N0 = blockIdx.y * 128;

    int srow = lane >> 2;            // 0..15
    int scol = (lane & 3) * 8;       // 0..24 ushorts

    f32x4 acc[4][4];
    #pragma unroll
    for (int i = 0; i < 4; ++i)
        #pragma unroll
        for (int j = 0; j < 4; ++j) acc[i][j] = (f32x4){0.f, 0.f, 0.f, 0.f};

    for (int k0 = 0; k0 < 1024; k0 += 32) {
        // stage A,B tiles: wave wid covers rows [32*wid, 32*wid+32), 2 calls each
        #pragma unroll
        for (int c = 0; c < 2; ++c) {
            int r = wid * 32 + c * 16 + srow;
            gl_lds16(A  + (size_t)(M0 + r) * 1024 + k0 + scol,
                     Al + wid * 1024 + c * 512);
            gl_lds16(Wt + (size_t)(N0 + r) * 1024 + k0 + scol,
                     Bl + wid * 1024 + c * 512);
        }
        __syncthreads();
        bf16x8 af[4], bf[4];
        #pragma unroll
        for (int mt = 0; mt < 4; ++mt)
            af[mt] = *(const bf16x8*)&Al[(wr * 64 + mt * 16 + jl) * 32 + quad * 8];
        #pragma unroll
        for (int nt = 0; nt < 4; ++nt)
            bf[nt] = *(const bf16x8*)&Bl[(wc * 64 + nt * 16 + jl) * 32 + quad * 8];
        #pragma unroll
        for (int mt = 0; mt < 4; ++mt)
            #pragma unroll
            for (int nt = 0; nt < 4; ++nt)
                acc[mt][nt] = MFMA16(af[mt], bf[nt], acc[mt][nt]);
        __syncthreads();
    }

    #pragma unroll
    for (int mt = 0; mt < 4; ++mt)
        #pragma unroll
        for (int nt = 0; nt < 4; ++nt)
            #pragma unroll
            for (int r = 0; r < 4; ++r) {
                int gm = M0 + wr * 64 + mt * 16 + quad * 4 + r;
                int gn = N0 + wc * 64 + nt * 16 + jl;
                float v = acc[mt][nt][r];
                if (omode == 0) {
                    int l = gm >> 1, b = gm & 1;
                    int h = gn >> 6, d = gn & 63;
                    size_t o = ((size_t)((b << 4) | h) * 1024 + l) * 64 + d;
                    outA[o] = f2bf(v + bu[gn]);
                    outB[o] = f2bf(v + bv[gn]);
                } else if (omode == 1) {
                    int t = gm >> 1, b = gm & 1;
                    int nn = gn & 1023;
                    int h = nn >> 6, d = nn & 63;
                    if (gn < 1024)
                        outA[((size_t)((b << 4) | h) * 2048 + t) * 64 + d] = f2bf(v);
                    else
                        outB[((size_t)((b << 4) | h) * 64 + d) * 2048 + t] = f2bf(v);
                } else if (omode == 2) {
                    int t = gm >> 1, b = gm & 1;
                    int h = gn >> 6, d = gn & 63;
                    outA[((size_t)((b << 4) | h) * 2048 + t) * 64 + d] = f2bf(v);
                } else {
                    outF[(size_t)gm * 1024 + gn] = v + resid[(size_t)gm * 1024 + gn];
                }
            }
}

// ---------------------------------------------------------------------------
// Barrier-free single-pass attention; XCD-bh binding + balanced wave decode.
// Work unit = one WAVE (16 q-rows, a contiguous chunk range). Per bh: 252
// wave-slots; i-tile it gets s=ceil(nc/7) segments (3/4/5), nc=17+it/4.
// Every wave processes 5-7 64-key chunks -> near-zero tail imbalance.
// ---------------------------------------------------------------------------
__global__ __launch_bounds__(256) void attn_fused5(
    const ushort* __restrict__ qu, const ushort* __restrict__ qv,
    const ushort* __restrict__ kb, const ushort* __restrict__ Vt,
    const ushort* __restrict__ rb,
    float* __restrict__ Opart, float* __restrict__ lpart,
    ushort* __restrict__ AMw)
{
    __shared__ ushort Pl[4][2][16][76];   // stride 38 dwords: b128 reads 2-way free

    int tid = threadIdx.x, wid = tid >> 6, lane = tid & 63;
    int quad = lane >> 4, jl = lane & 15;

    // balanced XCD-aware decode (round-robin dispatch heuristic, perf-only)
    int lin   = blockIdx.x;
    int xcd   = lin & 7;
    int bslot = lin >> 3;                // 0..251
    int q     = bslot * 4 + wid;         // 0..1007
    int bh_off = q / 252;
    int rem    = q - bh_off * 252;
    int it, seg, s;
    if (rem < 60)       { it = rem / 3;                  seg = rem - it * 3;        s = 3; }
    else if (rem < 172) { int t = rem - 60;  it = t >> 2; seg = t & 3; it += 20;    s = 4; }
    else                { int t = rem - 172; it = t / 5;  seg = t - it * 5; it += 48; s = 5; }
    int bh  = (xcd << 2) | bh_off;
    int i0w = it * 16;
    int nc  = 17 + (it >> 2);
    int cb_ = seg * nc / s;
    int ce_ = (seg + 1) * nc / s;
    int irow = i0w + quad * 4;

    const ushort* kp  = kb + (size_t)bh * 2048 * 64;
    const ushort* vtp = Vt + (size_t)bh * 64 * 2048;
    const ushort* rp  = rb + (size_t)bh * 2048 * 64;
    const ushort* qup = qu + (size_t)bh * 1024 * 64;
    const ushort* qvp = qv + (size_t)bh * 1024 * 64;

    bf16x8 quA[2], qvA[2];
    quA[0] = *(const bf16x8*)(qup + (size_t)(i0w + jl) * 64 + quad * 8);
    quA[1] = *(const bf16x8*)(qup + (size_t)(i0w + jl) * 64 + 32 + quad * 8);
    qvA[0] = *(const bf16x8*)(qvp + (size_t)(i0w + jl) * 64 + quad * 8);
    qvA[1] = *(const bf16x8*)(qvp + (size_t)(i0w + jl) * 64 + 32 + quad * 8);

    f32x4 z = (f32x4){0.f, 0.f, 0.f, 0.f};
    f32x4 oacc[4];
    #pragma unroll
    for (int nt = 0; nt < 4; ++nt) oacc[nt] = z;
    float lsum[4] = {0.f, 0.f, 0.f, 0.f};

    for (int c = cb_; c < ce_; ++c) {
        int j0 = c * 64;
        int par = c & 1;
        // ---- AC: 4 column-subtiles of 16 ----
        f32x4 ac[4];
        #pragma unroll
        for (int su = 0; su < 4; ++su) {
            const ushort* krow = kp + (size_t)(j0 + su * 16 + jl) * 64;
            bf16x8 k0 = *(const bf16x8*)(krow + quad * 8);
            bf16x8 k1 = *(const bf16x8*)(krow + 32 + quad * 8);
            f32x4 t = MFMA16(quA[0], k0, z);
            ac[su] = MFMA16(quA[1], k1, t);
        }
        // ---- BD windows: 5 n-tiles covering r-rows d0 .. d0+79 ----
        int d0 = 1008 + j0 - i0w;
        f32x4 bt[5];
        #pragma unroll
        for (int nt = 0; nt < 5; ++nt) {
            int rr = d0 + nt * 16 + jl;
            rr = min(max(rr, 0), 2047);
            const ushort* rrow = rp + (size_t)rr * 64;
            bf16x8 r0 = *(const bf16x8*)(rrow + quad * 8);
            bf16x8 r1 = *(const bf16x8*)(rrow + 32 + quad * 8);
            f32x4 t = MFMA16(qvA[0], r0, z);
            bt[nt] = MFMA16(qvA[1], r1, t);
        }
        // ---- diagonal extraction, exp, stage P ----
        #pragma unroll
        for (int r = 0; r < 4; ++r) {
            int ii = quad * 4 + r;
            int src = (quad << 4) | ((jl + 15 - ii) & 15);
            float bs[5];
            #pragma unroll
            for (int nt = 0; nt < 5; ++nt) bs[nt] = __shfl(bt[nt][r], src);
            bool hi = (jl > ii);      // nt = su + (jl > ii), same for all su
            #pragma unroll
            for (int su = 0; su < 4; ++su) {
                float bd = hi ? bs[su + 1] : bs[su];
                float sv = (ac[su][r] + bd) * SCALE_;
                int j = j0 + su * 16 + jl;
                float p = (j <= irow + r + M_) ? __expf(fminf(sv, 60.f)) : 0.f;
                lsum[r] += p;
                Pl[wid][par][ii][su * 16 + jl] = f2bf(p);
            }
        }
        asm volatile("s_waitcnt lgkmcnt(0)" ::: "memory");
        bf16x8 pA0 = *(const bf16x8*)&Pl[wid][par][jl][quad * 8];
        bf16x8 pA1 = *(const bf16x8*)&Pl[wid][par][jl][32 + quad * 8];
        // ---- plane write: 16 rows x 64 cols, 32 B/lane, non-temporal ----
        {
            int prow = lane >> 2, pcol = (lane & 3) * 16;
            u16x8v pv0 = *(const u16x8v*)&Pl[wid][par][prow][pcol];
            u16x8v pv1 = *(const u16x8v*)&Pl[wid][par][prow][pcol + 8];
            ushort* dst = AMw + (size_t)bh * 2097152 +
                          (size_t)(i0w + prow) * 2048 + j0 + pcol;
            __builtin_nontemporal_store(pv0, (u16x8v*)dst);
            __builtin_nontemporal_store(pv1, (u16x8v*)(dst + 8));
        }
        // ---- PV: 64 keys -> 2 MFMAs per 16-col d-tile ----
        #pragma unroll
        for (int nt = 0; nt < 4; ++nt) {
            const ushort* vrow = vtp + (size_t)(nt * 16 + jl) * 2048 + j0;
            bf16x8 vB0 = *(const bf16x8*)(vrow + quad * 8);
            bf16x8 vB1 = *(const bf16x8*)(vrow + 32 + quad * 8);
            oacc[nt] = MFMA16(pA0, vB0, oacc[nt]);
            oacc[nt] = MFMA16(pA1, vB1, oacc[nt]);
        }
    }

    // ---- epilogue: combine partials ----
    #pragma unroll
    for (int r = 0; r < 4; ++r) {
        #pragma unroll
        for (int off = 1; off < 16; off <<= 1) lsum[r] += __shfl_xor(lsum[r], off);
        if (jl == 0) atomicAdd(&lpart[(size_t)bh * 1024 + irow + r], lsum[r]);
    }
    #pragma unroll
    for (int nt = 0; nt < 4; ++nt)
        #pragma unroll
        for (int r = 0; r < 4; ++r)
            atomicAdd(&Opart[((size_t)bh * 1024 + irow + r) * 64 + nt * 16 + jl],
                      oacc[nt][r]);
}

// ---------------------------------------------------------------------------
// Combine O partials: O = Opart / l -> bf16 row-major [L*B][1024];
// also emit linvs[bh][i] = (1/l)/32 for am_reduce.
// ---------------------------------------------------------------------------
__global__ __launch_bounds__(256) void o_combine(
    const float* __restrict__ Opart, const float* __restrict__ lpart,
    ushort* __restrict__ OvecB, float* __restrict__ linvs)
{
    int idx8 = (blockIdx.x * 256 + threadIdx.x) * 8;   // over 2M floats
    int bh = idx8 >> 16;
    int rem = idx8 & 65535;
    int i = rem >> 6, d0 = rem & 63;
    float linv = 1.f / lpart[(size_t)bh * 1024 + i];
    float4 a = *(const float4*)(Opart + idx8);
    float4 b4 = *(const float4*)(Opart + idx8 + 4);
    u16x8v o;
    o[0] = f2bf(a.x * linv);  o[1] = f2bf(a.y * linv);
    o[2] = f2bf(a.z * linv);  o[3] = f2bf(a.w * linv);
    o[4] = f2bf(b4.x * linv); o[5] = f2bf(b4.y * linv);
    o[6] = f2bf(b4.z * linv); o[7] = f2bf(b4.w * linv);
    int b = bh >> 4, h = bh & 15;
    *(u16x8v*)(OvecB + (size_t)(i * 2 + b) * 1024 + h * 64 + d0) = o;
    if (d0 == 0) linvs[(size_t)bh * 1024 + i] = linv * 0.03125f;
}

// ---------------------------------------------------------------------------
// AM[i][j] = sum_bh plane[bh][i][j] * linvs[bh][i], re-masked.
// Skips the masked region. grid 2048 x 256 thr x 4 elems.
// ---------------------------------------------------------------------------
__global__ __launch_bounds__(256) void am_reduce(const ushort* __restrict__ AMw,
                                                 const float* __restrict__ linvs,
                                                 float* __restrict__ AM) {
    size_t idx = ((size_t)blockIdx.x * 256 + threadIdx.x) * 4;
    int i = (int)(idx >> 11);
    int j0 = (int)(idx & 2047);
    int jmax = i + M_;
    if (j0 > jmax) {
        *(float4*)(AM + idx) = (float4){0.f, 0.f, 0.f, 0.f};
        return;
    }
    float a0 = 0.f, a1 = 0.f, a2 = 0.f, a3 = 0.f;
    for (int p = 0; p < 32; ++p) {
        float lv = linvs[(size_t)p * 1024 + i];
        u16x4v v = __builtin_nontemporal_load(
            (const u16x4v*)(AMw + (size_t)p * 2097152 + idx));
        a0 += bf2f(v[0]) * lv;
        a1 += bf2f(v[1]) * lv;
        a2 += bf2f(v[2]) * lv;
        a3 += bf2f(v[3]) * lv;
    }
    float4 o;
    o.x = a0;
    o.y = (j0 + 1 <= jmax) ? a1 : 0.f;
    o.z = (j0 + 2 <= jmax) ? a2 : 0.f;
    o.w = (j0 + 3 <= jmax) ? a3 : 0.f;
    *(float4*)(AM + idx) = o;
}

// ---------------------------------------------------------------------------
// LayerNorm over D=1024, one block per row
// ---------------------------------------------------------------------------
__global__ __launch_bounds__(256) void ln_kernel(
    const float* __restrict__ hbuf,
    const float* __restrict__ gamma, const float* __restrict__ beta,
    float* __restrict__ out)
{
    __shared__ float rs[4], rss[4];
    int row = blockIdx.x;
    int tid = threadIdx.x;
    const float* hp = hbuf + (size_t)row * 1024;
    float4 h4 = *(const float4*)(hp + (tid << 2));
    float s = h4.x + h4.y + h4.z + h4.w;
    float ss = h4.x * h4.x + h4.y * h4.y + h4.z * h4.z + h4.w * h4.w;
    #pragma unroll
    for (int o = 32; o > 0; o >>= 1) {
        s  += __shfl_down(s, o);
        ss += __shfl_down(ss, o);
    }
    if ((tid & 63) == 0) { rs[tid >> 6] = s; rss[tid >> 6] = ss; }
    __syncthreads();
    float tot  = rs[0] + rs[1] + rs[2] + rs[3];
    float tots = rss[0] + rss[1] + rss[2] + rss[3];
    float mu = tot * (1.f / 1024.f);
    float var = tots * (1.f / 1024.f) - mu * mu;
    float rstd = rsqrtf(var + 1e-5f);
    float4 g4 = *(const float4*)(gamma + (tid << 2));
    float4 b4 = *(const float4*)(beta + (tid << 2));
    float4 o4;
    o4.x = (h4.x - mu) * rstd * g4.x + b4.x;
    o4.y = (h4.y - mu) * rstd * g4.y + b4.y;
    o4.z = (h4.z - mu) * rstd * g4.z + b4.z;
    o4.w = (h4.w - mu) * rstd * g4.w + b4.w;
    *(float4*)(out + (size_t)row * 1024 + (tid << 2)) = o4;
}

extern "C" void kernel_launch(void* const* d_in, const int* in_sizes, int n_in,
                              void* d_out, int out_size, void* d_ws, size_t ws_size,
                              hipStream_t stream) {
    const float* x       = (const float*)d_in[0];
    const float* pos_emb = (const float*)d_in[1];
    const float* memory  = (const float*)d_in[2];
    const float* bu      = (const float*)d_in[3];
    const float* bv      = (const float*)d_in[4];
    const float* Wq      = (const float*)d_in[6];
    const float* Wkv     = (const float*)d_in[7];
    const float* Wrel    = (const float*)d_in[8];
    const float* Wo      = (const float*)d_in[9];
    const float* gamma   = (const float*)d_in[10];
    const float* beta    = (const float*)d_in[11];

    float* out = (float*)d_out;
    float* AM  = out + (size_t)2097152;       // attn_matrix [L][T]

    ushort* cb    = (ushort*)d_ws;            // [4096][1024]
    ushort* pb    = cb    + 4194304;          // [4096][1024]
    ushort* Wqt   = pb    + 4194304;          // [1024][1024]
    ushort* Wkvt  = Wqt   + 1048576;          // [2048][1024]
    ushort* Wrelt = Wkvt  + 2097152;          // [1024][1024]
    ushort* Wot   = Wrelt + 1048576;          // [1024][1024]
    ushort* quB   = Wot   + 1048576;          // [32][1024][64]
    ushort* qvB   = quB   + 2097152;
    ushort* kbB   = qvB   + 2097152;          // [32][2048][64]
    ushort* VtB   = kbB   + 4194304;          // [32][64][2048]
    ushort* rbB   = VtB   + 4194304;          // [32][2048][64]
    ushort* OvecB = rbB   + 4194304;          // [2048][1024]
    float*  hbuf  = (float*)(OvecB + 2097152);// [2048][1024] fp32
    float*  Opart = hbuf  + 2097152;          // [32][1024][64] fp32
    float*  lpart = Opart + 2097152;          // [32][1024] fp32
    float*  linvs = lpart + 32768;            // [32][1024] fp32
    ushort* AMw   = (ushort*)(linvs + 32768); // [32][1024][2048] bf16 (128 MB)

    dim3 blk(256);
    // converts
    cvt_bf16<<<1024, blk, 0, stream>>>(memory, cb, 2097152);
    cvt_bf16<<<1024, blk, 0, stream>>>(x, cb + 2097152, 2097152);
    cvt_bf16<<<2048, blk, 0, stream>>>(pos_emb, pb, 4194304);
    trans_cvt<<<dim3(32, 32), blk, 0, stream>>>(Wq,   Wqt,   1024, 1024);
    trans_cvt<<<dim3(32, 64), blk, 0, stream>>>(Wkv,  Wkvt,  1024, 2048);
    trans_cvt<<<dim3(32, 32), blk, 0, stream>>>(Wrel, Wrelt, 1024, 1024);
    trans_cvt<<<dim3(32, 32), blk, 0, stream>>>(Wo,   Wot,   1024, 1024);
    hipMemsetAsync(Opart, 0, (size_t)2097152 * sizeof(float), stream);
    hipMemsetAsync(lpart, 0, (size_t)32768 * sizeof(float), stream);

    // projections (128x128-tile MFMA GEMM)
    gemm128<<<dim3(16, 8), blk, 0, stream>>>(cb + 2097152, Wqt, 0, bu, bv,
                                             quB, qvB, nullptr, nullptr);
    gemm128<<<dim3(32, 16), blk, 0, stream>>>(cb, Wkvt, 1, nullptr, nullptr,
                                              kbB, VtB, nullptr, nullptr);
    gemm128<<<dim3(32, 8), blk, 0, stream>>>(pb, Wrelt, 2, nullptr, nullptr,
                                             rbB, nullptr, nullptr, nullptr);
    // attention (barrier-free, balanced wave decode, XCD-bh binding)
    attn_fused5<<<dim3(2016), blk, 0, stream>>>(quB, qvB, kbB, VtB, rbB,
                                                Opart, lpart, AMw);
    // combine partials -> OvecB + linvs
    o_combine<<<1024, blk, 0, stream>>>(Opart, lpart, OvecB, linvs);
    // output projection + residual
    gemm128<<<dim3(16, 8), blk, 0, stream>>>(OvecB, Wot, 3, nullptr, nullptr,
                                             nullptr, nullptr, x, hbuf);
    // layernorm
    ln_kernel<<<2048, blk, 0, stream>>>(hbuf, gamma, beta, out);
    // attn_matrix reduction
    am_reduce<<<2048, blk, 0, stream>>>(AMw, linvs, AM);
}

// Round 7
// 456.534 us; speedup vs baseline: 1.0356x; 1.0356x over previous
//
#include <hip/hip_runtime.h>
#include <math.h>
#include <stdint.h>

#define L_  1024
#define B_  2
#define D_  1024
#define H_  16
#define DH_ 64
#define M_  1024
#define T_  2048
#define SCALE_ 0.125f

typedef unsigned short ushort;
typedef short bf16x8 __attribute__((ext_vector_type(8)));
typedef float f32x4 __attribute__((ext_vector_type(4)));
typedef unsigned short u16x4v __attribute__((ext_vector_type(4)));
typedef unsigned short u16x8v __attribute__((ext_vector_type(8)));

#define MFMA16(a,b,c) __builtin_amdgcn_mfma_f32_16x16x32_bf16(a,b,c,0,0,0)

static __device__ __forceinline__ ushort f2bf(float x) {
    uint32_t u = __float_as_uint(x);
    uint32_t r = (u + 0x7FFFu + ((u >> 16) & 1u)) >> 16;
    return (ushort)r;
}
static __device__ __forceinline__ float bf2f(ushort h) {
    return __uint_as_float(((uint32_t)h) << 16);
}
// async global->LDS, 16B per lane; LDS dest = wave-uniform base + lane*16
static __device__ __forceinline__ void gl_lds16(const ushort* g, ushort* l) {
    __builtin_amdgcn_global_load_lds(
        (const __attribute__((address_space(1))) void*)g,
        (__attribute__((address_space(3))) void*)l, 16, 0, 0);
}

// ---------------------------------------------------------------------------
// Fused fp32 -> bf16 convert for memory/x/pos_emb (8M elements, grid 4096)
// ---------------------------------------------------------------------------
__global__ __launch_bounds__(256) void cvt_all(
    const float* __restrict__ memory, const float* __restrict__ x,
    const float* __restrict__ pos_emb,
    ushort* __restrict__ cb, ushort* __restrict__ pb)
{
    int idx = (blockIdx.x * 256 + threadIdx.x) * 8;
    const float* s;
    ushort* d;
    if (idx < 2097152)      { s = memory + idx;             d = cb + idx; }
    else if (idx < 4194304) { s = x + (idx - 2097152);      d = cb + idx; }
    else                    { s = pos_emb + (idx - 4194304); d = pb + (idx - 4194304); }
    float4 a = *(const float4*)(s);
    float4 b = *(const float4*)(s + 4);
    u16x8v o;
    o[0] = f2bf(a.x); o[1] = f2bf(a.y); o[2] = f2bf(a.z); o[3] = f2bf(a.w);
    o[4] = f2bf(b.x); o[5] = f2bf(b.y); o[6] = f2bf(b.z); o[7] = f2bf(b.w);
    *(u16x8v*)d = o;
}

// ---------------------------------------------------------------------------
// Fused weight transpose+convert: fp32 [1024][N] -> bf16 [N][1024].
// Flat grid 5120: Wq(1024) | Wkv(2048) | Wrel(1024) | Wo(1024) 32x32 tiles.
// ---------------------------------------------------------------------------
__global__ __launch_bounds__(256) void trans_all(
    const float* __restrict__ Wq, const float* __restrict__ Wkv,
    const float* __restrict__ Wrel, const float* __restrict__ Wo,
    ushort* __restrict__ Wqt, ushort* __restrict__ Wkvt,
    ushort* __restrict__ Wrelt, ushort* __restrict__ Wot)
{
    __shared__ float t[32][33];
    int tb = blockIdx.x;
    const float* src; ushort* dst; int N;
    if (tb < 1024)      { src = Wq;   dst = Wqt;   N = 1024; }
    else if (tb < 3072) { src = Wkv;  dst = Wkvt;  N = 2048; tb -= 1024; }
    else if (tb < 4096) { src = Wrel; dst = Wrelt; N = 1024; tb -= 3072; }
    else                { src = Wo;   dst = Wot;   N = 1024; tb -= 4096; }
    int k0 = (tb & 31) * 32, n0 = (tb >> 5) * 32;
    int tid = threadIdx.x;
    int r = tid >> 3, c4 = (tid & 7) * 4;
    float4 v = *(const float4*)(src + (size_t)(k0 + r) * N + n0 + c4);
    t[r][c4 + 0] = v.x; t[r][c4 + 1] = v.y; t[r][c4 + 2] = v.z; t[r][c4 + 3] = v.w;
    __syncthreads();
    u16x4v o;
    o[0] = f2bf(t[c4 + 0][r]); o[1] = f2bf(t[c4 + 1][r]);
    o[2] = f2bf(t[c4 + 2][r]); o[3] = f2bf(t[c4 + 3][r]);
    *(u16x4v*)(dst + (size_t)(n0 + r) * 1024 + k0 + c4) = o;
}

// ---------------------------------------------------------------------------
// 64x64-tile bf16 MFMA GEMM (512 blocks for q/o: full-machine occupancy).
// omode 0: q -> qu=(+bu), qv=(+bv), layout [bh][L][64]
// omode 3: outF[m][n] = acc + resid  (fp32)
// ---------------------------------------------------------------------------
__global__ __launch_bounds__(256) void gemm_bf16(
    const ushort* __restrict__ A, const ushort* __restrict__ Wt,
    int omode,
    const float* __restrict__ bu, const float* __restrict__ bv,
    ushort* __restrict__ outA, ushort* __restrict__ outB,
    const float* __restrict__ resid, float* __restrict__ outF)
{
    __shared__ ushort Al[64][40];
    __shared__ ushort Bl[64][40];
    int tid = threadIdx.x;
    int M0 = blockIdx.x * 64, N0 = blockIdx.y * 64;
    int wid = tid >> 6, lane = tid & 63, quad = lane >> 4, jl = lane & 15;
    int m0w = (wid >> 1) * 32, n0w = (wid & 1) * 32;
    int sr = tid >> 2, sc = (tid & 3) * 8;

    f32x4 acc[2][2];
    #pragma unroll
    for (int i = 0; i < 2; ++i)
        #pragma unroll
        for (int j = 0; j < 2; ++j) acc[i][j] = (f32x4){0.f, 0.f, 0.f, 0.f};

    for (int k0 = 0; k0 < 1024; k0 += 32) {
        *(u16x8v*)&Al[sr][sc] = *(const u16x8v*)(A  + (size_t)(M0 + sr) * 1024 + k0 + sc);
        *(u16x8v*)&Bl[sr][sc] = *(const u16x8v*)(Wt + (size_t)(N0 + sr) * 1024 + k0 + sc);
        __syncthreads();
        bf16x8 a0 = *(const bf16x8*)&Al[m0w + jl][quad * 8];
        bf16x8 a1 = *(const bf16x8*)&Al[m0w + 16 + jl][quad * 8];
        bf16x8 b0 = *(const bf16x8*)&Bl[n0w + jl][quad * 8];
        bf16x8 b1 = *(const bf16x8*)&Bl[n0w + 16 + jl][quad * 8];
        acc[0][0] = MFMA16(a0, b0, acc[0][0]);
        acc[0][1] = MFMA16(a0, b1, acc[0][1]);
        acc[1][0] = MFMA16(a1, b0, acc[1][0]);
        acc[1][1] = MFMA16(a1, b1, acc[1][1]);
        __syncthreads();
    }

    #pragma unroll
    for (int ms = 0; ms < 2; ++ms)
        #pragma unroll
        for (int ns = 0; ns < 2; ++ns)
            #pragma unroll
            for (int r = 0; r < 4; ++r) {
                int gm = M0 + m0w + 16 * ms + quad * 4 + r;
                int gn = N0 + n0w + 16 * ns + jl;
                float v = acc[ms][ns][r];
                if (omode == 0) {
                    int l = gm >> 1, b = gm & 1;
                    int h = gn >> 6, d = gn & 63;
                    size_t o = ((size_t)((b << 4) | h) * 1024 + l) * 64 + d;
                    outA[o] = f2bf(v + bu[gn]);
                    outB[o] = f2bf(v + bv[gn]);
                } else {
                    outF[(size_t)gm * 1024 + gn] = v + resid[(size_t)gm * 1024 + gn];
                }
            }
}

// ---------------------------------------------------------------------------
// 128x128-tile bf16 MFMA GEMM (m97 structure) for kv / r projections.
// omode 1: kv -> n<1024: k row-major [bh][T][64]; else v TRANSPOSED [bh][64][T]
// omode 2: r -> [bh][T][64]
// ---------------------------------------------------------------------------
__global__ __launch_bounds__(256) void gemm128(
    const ushort* __restrict__ A, const ushort* __restrict__ Wt,
    int omode,
    ushort* __restrict__ outA, ushort* __restrict__ outB)
{
    __shared__ ushort Al[128 * 32];
    __shared__ ushort Bl[128 * 32];
    int tid = threadIdx.x;
    int wid = tid >> 6, lane = tid & 63, quad = lane >> 4, jl = lane & 15;
    int wr = wid >> 1, wc = wid & 1;
    int M0 = blockIdx.x * 128, N0 = blockIdx.y * 128;

    int srow = lane >> 2;
    int scol = (lane & 3) * 8;

    f32x4 acc[4][4];
    #pragma unroll
    for (int i = 0; i < 4; ++i)
        #pragma unroll
        for (int j = 0; j < 4; ++j) acc[i][j] = (f32x4){0.f, 0.f, 0.f, 0.f};

    for (int k0 = 0; k0 < 1024; k0 += 32) {
        #pragma unroll
        for (int c = 0; c < 2; ++c) {
            int r = wid * 32 + c * 16 + srow;
            gl_lds16(A  + (size_t)(M0 + r) * 1024 + k0 + scol,
                     Al + wid * 1024 + c * 512);
            gl_lds16(Wt + (size_t)(N0 + r) * 1024 + k0 + scol,
                     Bl + wid * 1024 + c * 512);
        }
        __syncthreads();
        bf16x8 af[4], bfr[4];
        #pragma unroll
        for (int mt = 0; mt < 4; ++mt)
            af[mt] = *(const bf16x8*)&Al[(wr * 64 + mt * 16 + jl) * 32 + quad * 8];
        #pragma unroll
        for (int nt = 0; nt < 4; ++nt)
            bfr[nt] = *(const bf16x8*)&Bl[(wc * 64 + nt * 16 + jl) * 32 + quad * 8];
        #pragma unroll
        for (int mt = 0; mt < 4; ++mt)
            #pragma unroll
            for (int nt = 0; nt < 4; ++nt)
                acc[mt][nt] = MFMA16(af[mt], bfr[nt], acc[mt][nt]);
        __syncthreads();
    }

    #pragma unroll
    for (int mt = 0; mt < 4; ++mt)
        #pragma unroll
        for (int nt = 0; nt < 4; ++nt)
            #pragma unroll
            for (int r = 0; r < 4; ++r) {
                int gm = M0 + wr * 64 + mt * 16 + quad * 4 + r;
                int gn = N0 + wc * 64 + nt * 16 + jl;
                float v = acc[mt][nt][r];
                int t = gm >> 1, b = gm & 1;
                if (omode == 1) {
                    int nn = gn & 1023;
                    int h = nn >> 6, d = nn & 63;
                    if (gn < 1024)
                        outA[((size_t)((b << 4) | h) * 2048 + t) * 64 + d] = f2bf(v);
                    else
                        outB[((size_t)((b << 4) | h) * 64 + d) * 2048 + t] = f2bf(v);
                } else {
                    int h = gn >> 6, d = gn & 63;
                    outA[((size_t)((b << 4) | h) * 2048 + t) * 64 + d] = f2bf(v);
                }
            }
}

// ---------------------------------------------------------------------------
// Barrier-free single-pass attention; XCD-bh binding, j-split x2, V hoisted.
// Planes laid out [i][bh][j] so am_reduce streams contiguously.
// ---------------------------------------------------------------------------
__global__ __launch_bounds__(256) void attn_fused6(
    const ushort* __restrict__ qu, const ushort* __restrict__ qv,
    const ushort* __restrict__ kb, const ushort* __restrict__ Vt,
    const ushort* __restrict__ rb,
    float* __restrict__ Opart, float* __restrict__ lpart,
    ushort* __restrict__ AMw)
{
    __shared__ ushort Pl[4][2][16][76];

    int tid = threadIdx.x, wid = tid >> 6, lane = tid & 63;
    int quad = lane >> 4, jl = lane & 15;

    // XCD-aware decode: xcd owns 4 bh; per wave: (bh, i-tile, seg of 2)
    int lin   = blockIdx.x;            // 0..1023
    int xcd   = lin & 7;
    int bslot = lin >> 3;              // 0..127
    int q     = bslot * 4 + wid;       // 0..511
    int bh_off = q >> 7;               // 0..3
    int rem    = q & 127;
    int it  = rem >> 1;                // 0..63
    int seg = rem & 1;
    int bh  = (xcd << 2) | bh_off;
    int i0w = it * 16;
    int nc  = 17 + (it >> 2);
    int cb_ = seg * nc / 2;
    int ce_ = (seg + 1) * nc / 2;
    int irow = i0w + quad * 4;

    const ushort* kp  = kb + (size_t)bh * 2048 * 64;
    const ushort* vtp = Vt + (size_t)bh * 64 * 2048;
    const ushort* rp  = rb + (size_t)bh * 2048 * 64;
    const ushort* qup = qu + (size_t)bh * 1024 * 64;
    const ushort* qvp = qv + (size_t)bh * 1024 * 64;

    bf16x8 quA[2], qvA[2];
    quA[0] = *(const bf16x8*)(qup + (size_t)(i0w + jl) * 64 + quad * 8);
    quA[1] = *(const bf16x8*)(qup + (size_t)(i0w + jl) * 64 + 32 + quad * 8);
    qvA[0] = *(const bf16x8*)(qvp + (size_t)(i0w + jl) * 64 + quad * 8);
    qvA[1] = *(const bf16x8*)(qvp + (size_t)(i0w + jl) * 64 + 32 + quad * 8);

    f32x4 z = (f32x4){0.f, 0.f, 0.f, 0.f};
    f32x4 oacc[4];
    #pragma unroll
    for (int nt = 0; nt < 4; ++nt) oacc[nt] = z;
    float lsum[4] = {0.f, 0.f, 0.f, 0.f};

    for (int c = cb_; c < ce_; ++c) {
        int j0 = c * 64;
        int par = c & 1;
        // ---- V hoist: issue PV operand loads first (overlap with AC/BD) ----
        bf16x8 vB[8];
        #pragma unroll
        for (int nt = 0; nt < 4; ++nt) {
            const ushort* vrow = vtp + (size_t)(nt * 16 + jl) * 2048 + j0;
            vB[2 * nt]     = *(const bf16x8*)(vrow + quad * 8);
            vB[2 * nt + 1] = *(const bf16x8*)(vrow + 32 + quad * 8);
        }
        // ---- AC: 4 column-subtiles of 16 ----
        f32x4 ac[4];
        #pragma unroll
        for (int su = 0; su < 4; ++su) {
            const ushort* krow = kp + (size_t)(j0 + su * 16 + jl) * 64;
            bf16x8 k0 = *(const bf16x8*)(krow + quad * 8);
            bf16x8 k1 = *(const bf16x8*)(krow + 32 + quad * 8);
            f32x4 t = MFMA16(quA[0], k0, z);
            ac[su] = MFMA16(quA[1], k1, t);
        }
        // ---- BD windows: 5 n-tiles covering r-rows d0 .. d0+79 ----
        int d0 = 1008 + j0 - i0w;
        f32x4 bt[5];
        #pragma unroll
        for (int nt = 0; nt < 5; ++nt) {
            int rr = d0 + nt * 16 + jl;
            rr = min(max(rr, 0), 2047);
            const ushort* rrow = rp + (size_t)rr * 64;
            bf16x8 r0 = *(const bf16x8*)(rrow + quad * 8);
            bf16x8 r1 = *(const bf16x8*)(rrow + 32 + quad * 8);
            f32x4 t = MFMA16(qvA[0], r0, z);
            bt[nt] = MFMA16(qvA[1], r1, t);
        }
        // ---- diagonal extraction, exp, stage P ----
        #pragma unroll
        for (int r = 0; r < 4; ++r) {
            int ii = quad * 4 + r;
            int src = (quad << 4) | ((jl + 15 - ii) & 15);
            float bs[5];
            #pragma unroll
            for (int nt = 0; nt < 5; ++nt) bs[nt] = __shfl(bt[nt][r], src);
            bool hi = (jl > ii);
            #pragma unroll
            for (int su = 0; su < 4; ++su) {
                float bd = hi ? bs[su + 1] : bs[su];
                float sv = (ac[su][r] + bd) * SCALE_;
                int j = j0 + su * 16 + jl;
                float p = (j <= irow + r + M_) ? __expf(fminf(sv, 60.f)) : 0.f;
                lsum[r] += p;
                Pl[wid][par][ii][su * 16 + jl] = f2bf(p);
            }
        }
        asm volatile("s_waitcnt lgkmcnt(0)" ::: "memory");
        bf16x8 pA0 = *(const bf16x8*)&Pl[wid][par][jl][quad * 8];
        bf16x8 pA1 = *(const bf16x8*)&Pl[wid][par][jl][32 + quad * 8];
        // ---- plane write to [i][bh][j]: 16 rows x 64 cols, NT ----
        {
            int prow = lane >> 2, pcol = (lane & 3) * 16;
            u16x8v pv0 = *(const u16x8v*)&Pl[wid][par][prow][pcol];
            u16x8v pv1 = *(const u16x8v*)&Pl[wid][par][prow][pcol + 8];
            ushort* dst = AMw + ((size_t)(i0w + prow) * 32 + bh) * 2048 + j0 + pcol;
            __builtin_nontemporal_store(pv0, (u16x8v*)dst);
            __builtin_nontemporal_store(pv1, (u16x8v*)(dst + 8));
        }
        // ---- PV (uses hoisted vB) ----
        #pragma unroll
        for (int nt = 0; nt < 4; ++nt) {
            oacc[nt] = MFMA16(pA0, vB[2 * nt], oacc[nt]);
            oacc[nt] = MFMA16(pA1, vB[2 * nt + 1], oacc[nt]);
        }
    }

    // ---- epilogue: combine partials ----
    #pragma unroll
    for (int r = 0; r < 4; ++r) {
        #pragma unroll
        for (int off = 1; off < 16; off <<= 1) lsum[r] += __shfl_xor(lsum[r], off);
        if (jl == 0) atomicAdd(&lpart[(size_t)bh * 1024 + irow + r], lsum[r]);
    }
    #pragma unroll
    for (int nt = 0; nt < 4; ++nt)
        #pragma unroll
        for (int r = 0; r < 4; ++r)
            atomicAdd(&Opart[((size_t)bh * 1024 + irow + r) * 64 + nt * 16 + jl],
                      oacc[nt][r]);
}

// ---------------------------------------------------------------------------
// Combine O partials: O = Opart / l -> bf16 row-major [L*B][1024];
// emit linvs[i][bh] = (1/l)/32 for am_reduce.
// ---------------------------------------------------------------------------
__global__ __launch_bounds__(256) void o_combine(
    const float* __restrict__ Opart, const float* __restrict__ lpart,
    ushort* __restrict__ OvecB, float* __restrict__ linvs)
{
    int idx8 = (blockIdx.x * 256 + threadIdx.x) * 8;
    int bh = idx8 >> 16;
    int rem = idx8 & 65535;
    int i = rem >> 6, d0 = rem & 63;
    float linv = 1.f / lpart[(size_t)bh * 1024 + i];
    float4 a = *(const float4*)(Opart + idx8);
    float4 b4 = *(const float4*)(Opart + idx8 + 4);
    u16x8v o;
    o[0] = f2bf(a.x * linv);  o[1] = f2bf(a.y * linv);
    o[2] = f2bf(a.z * linv);  o[3] = f2bf(a.w * linv);
    o[4] = f2bf(b4.x * linv); o[5] = f2bf(b4.y * linv);
    o[6] = f2bf(b4.z * linv); o[7] = f2bf(b4.w * linv);
    int b = bh >> 4, h = bh & 15;
    *(u16x8v*)(OvecB + (size_t)(i * 2 + b) * 1024 + h * 64 + d0) = o;
    if (d0 == 0) linvs[(size_t)i * 32 + bh] = linv * 0.03125f;
}

// ---------------------------------------------------------------------------
// AM[i][j] = sum_bh plane[i][bh][j] * linvs[i][bh], re-masked.
// One block per row i: fully contiguous 128 KB stream per block.
// ---------------------------------------------------------------------------
__global__ __launch_bounds__(256) void am_reduce(const ushort* __restrict__ AMw,
                                                 const float* __restrict__ linvs,
                                                 float* __restrict__ AM) {
    __shared__ float lv[32];
    int i = blockIdx.x;
    int tid = threadIdx.x;
    if (tid < 32) lv[tid] = linvs[(size_t)i * 32 + tid];
    __syncthreads();
    int j0 = tid * 8;
    int jmax = i + M_;
    float acc[8];
    #pragma unroll
    for (int e = 0; e < 8; ++e) acc[e] = 0.f;
    if (j0 <= jmax) {
        const ushort* base = AMw + (size_t)i * 65536;
        for (int p = 0; p < 32; ++p) {
            float l = lv[p];
            u16x8v v = __builtin_nontemporal_load(
                (const u16x8v*)(base + (size_t)p * 2048 + j0));
            #pragma unroll
            for (int e = 0; e < 8; ++e) acc[e] += bf2f(v[e]) * l;
        }
    }
    float4 o0, o1;
    o0.x = (j0 + 0 <= jmax) ? acc[0] : 0.f;
    o0.y = (j0 + 1 <= jmax) ? acc[1] : 0.f;
    o0.z = (j0 + 2 <= jmax) ? acc[2] : 0.f;
    o0.w = (j0 + 3 <= jmax) ? acc[3] : 0.f;
    o1.x = (j0 + 4 <= jmax) ? acc[4] : 0.f;
    o1.y = (j0 + 5 <= jmax) ? acc[5] : 0.f;
    o1.z = (j0 + 6 <= jmax) ? acc[6] : 0.f;
    o1.w = (j0 + 7 <= jmax) ? acc[7] : 0.f;
    *(float4*)(AM + (size_t)i * 2048 + j0) = o0;
    *(float4*)(AM + (size_t)i * 2048 + j0 + 4) = o1;
}

// ---------------------------------------------------------------------------
// LayerNorm over D=1024, one block per row
// ---------------------------------------------------------------------------
__global__ __launch_bounds__(256) void ln_kernel(
    const float* __restrict__ hbuf,
    const float* __restrict__ gamma, const float* __restrict__ beta,
    float* __restrict__ out)
{
    __shared__ float rs[4], rss[4];
    int row = blockIdx.x;
    int tid = threadIdx.x;
    const float* hp = hbuf + (size_t)row * 1024;
    float4 h4 = *(const float4*)(hp + (tid << 2));
    float s = h4.x + h4.y + h4.z + h4.w;
    float ss = h4.x * h4.x + h4.y * h4.y + h4.z * h4.z + h4.w * h4.w;
    #pragma unroll
    for (int o = 32; o > 0; o >>= 1) {
        s  += __shfl_down(s, o);
        ss += __shfl_down(ss, o);
    }
    if ((tid & 63) == 0) { rs[tid >> 6] = s; rss[tid >> 6] = ss; }
    __syncthreads();
    float tot  = rs[0] + rs[1] + rs[2] + rs[3];
    float tots = rss[0] + rss[1] + rss[2] + rss[3];
    float mu = tot * (1.f / 1024.f);
    float var = tots * (1.f / 1024.f) - mu * mu;
    float rstd = rsqrtf(var + 1e-5f);
    float4 g4 = *(const float4*)(gamma + (tid << 2));
    float4 b4 = *(const float4*)(beta + (tid << 2));
    float4 o4;
    o4.x = (h4.x - mu) * rstd * g4.x + b4.x;
    o4.y = (h4.y - mu) * rstd * g4.y + b4.y;
    o4.z = (h4.z - mu) * rstd * g4.z + b4.z;
    o4.w = (h4.w - mu) * rstd * g4.w + b4.w;
    *(float4*)(out + (size_t)row * 1024 + (tid << 2)) = o4;
}

extern "C" void kernel_launch(void* const* d_in, const int* in_sizes, int n_in,
                              void* d_out, int out_size, void* d_ws, size_t ws_size,
                              hipStream_t stream) {
    const float* x       = (const float*)d_in[0];
    const float* pos_emb = (const float*)d_in[1];
    const float* memory  = (const float*)d_in[2];
    const float* bu      = (const float*)d_in[3];
    const float* bv      = (const float*)d_in[4];
    const float* Wq      = (const float*)d_in[6];
    const float* Wkv     = (const float*)d_in[7];
    const float* Wrel    = (const float*)d_in[8];
    const float* Wo      = (const float*)d_in[9];
    const float* gamma   = (const float*)d_in[10];
    const float* beta    = (const float*)d_in[11];

    float* out = (float*)d_out;
    float* AM  = out + (size_t)2097152;       // attn_matrix [L][T]

    ushort* cb    = (ushort*)d_ws;            // [4096][1024]
    ushort* pb    = cb    + 4194304;          // [4096][1024]
    ushort* Wqt   = pb    + 4194304;          // [1024][1024]
    ushort* Wkvt  = Wqt   + 1048576;          // [2048][1024]
    ushort* Wrelt = Wkvt  + 2097152;          // [1024][1024]
    ushort* Wot   = Wrelt + 1048576;          // [1024][1024]
    ushort* quB   = Wot   + 1048576;          // [32][1024][64]
    ushort* qvB   = quB   + 2097152;
    ushort* kbB   = qvB   + 2097152;          // [32][2048][64]
    ushort* VtB   = kbB   + 4194304;          // [32][64][2048]
    ushort* rbB   = VtB   + 4194304;          // [32][2048][64]
    ushort* OvecB = rbB   + 4194304;          // [2048][1024]
    float*  hbuf  = (float*)(OvecB + 2097152);// [2048][1024] fp32
    float*  Opart = hbuf  + 2097152;          // [32][1024][64] fp32
    float*  lpart = Opart + 2097152;          // [32][1024] fp32
    float*  linvs = lpart + 32768;            // [1024][32] fp32
    ushort* AMw   = (ushort*)(linvs + 32768); // [1024][32][2048] bf16 (128 MB)

    dim3 blk(256);
    // fused converts
    cvt_all<<<4096, blk, 0, stream>>>(memory, x, pos_emb, cb, pb);
    trans_all<<<5120, blk, 0, stream>>>(Wq, Wkv, Wrel, Wo, Wqt, Wkvt, Wrelt, Wot);
    hipMemsetAsync(Opart, 0, (size_t)2097152 * sizeof(float), stream);
    hipMemsetAsync(lpart, 0, (size_t)32768 * sizeof(float), stream);

    // projections
    gemm_bf16<<<dim3(32, 16), blk, 0, stream>>>(cb + 2097152, Wqt, 0, bu, bv,
                                                quB, qvB, nullptr, nullptr);
    gemm128<<<dim3(32, 16), blk, 0, stream>>>(cb, Wkvt, 1, kbB, VtB);
    gemm128<<<dim3(32, 8), blk, 0, stream>>>(pb, Wrelt, 2, rbB, nullptr);
    // attention (barrier-free, j-split x2, XCD-bh binding, V hoisted)
    attn_fused6<<<dim3(1024), blk, 0, stream>>>(quB, qvB, kbB, VtB, rbB,
                                                Opart, lpart, AMw);
    // combine partials -> OvecB + linvs
    o_combine<<<1024, blk, 0, stream>>>(Opart, lpart, OvecB, linvs);
    // output projection + residual
    gemm_bf16<<<dim3(32, 16), blk, 0, stream>>>(OvecB, Wot, 3, nullptr, nullptr,
                                                nullptr, nullptr, x, hbuf);
    // layernorm
    ln_kernel<<<2048, blk, 0, stream>>>(hbuf, gamma, beta, out);
    // attn_matrix reduction (streaming)
    am_reduce<<<1024, blk, 0, stream>>>(AMw, linvs, AM);
}

// Round 8
// 419.161 us; speedup vs baseline: 1.1279x; 1.0892x over previous
//
#include <hip/hip_runtime.h>
#include <math.h>
#include <stdint.h>

#define L_  1024
#define B_  2
#define D_  1024
#define H_  16
#define DH_ 64
#define M_  1024
#define T_  2048
#define SCALE_ 0.125f

typedef unsigned short ushort;
typedef short bf16x8 __attribute__((ext_vector_type(8)));
typedef float f32x4 __attribute__((ext_vector_type(4)));
typedef unsigned short u16x4v __attribute__((ext_vector_type(4)));
typedef unsigned short u16x8v __attribute__((ext_vector_type(8)));

#define MFMA16(a,b,c) __builtin_amdgcn_mfma_f32_16x16x32_bf16(a,b,c,0,0,0)

static __device__ __forceinline__ ushort f2bf(float x) {
    uint32_t u = __float_as_uint(x);
    uint32_t r = (u + 0x7FFFu + ((u >> 16) & 1u)) >> 16;
    return (ushort)r;
}
static __device__ __forceinline__ float bf2f(ushort h) {
    return __uint_as_float(((uint32_t)h) << 16);
}
// async global->LDS, 16B per lane; LDS dest = wave-uniform base + lane*16
static __device__ __forceinline__ void gl_lds16(const ushort* g, ushort* l) {
    __builtin_amdgcn_global_load_lds(
        (const __attribute__((address_space(1))) void*)g,
        (__attribute__((address_space(3))) void*)l, 16, 0, 0);
}

// ---------------------------------------------------------------------------
// Fused fp32 -> bf16 convert for memory/x/pos_emb (8M elements, grid 4096)
// ---------------------------------------------------------------------------
__global__ __launch_bounds__(256) void cvt_all(
    const float* __restrict__ memory, const float* __restrict__ x,
    const float* __restrict__ pos_emb,
    ushort* __restrict__ cb, ushort* __restrict__ pb)
{
    int idx = (blockIdx.x * 256 + threadIdx.x) * 8;
    const float* s;
    ushort* d;
    if (idx < 2097152)      { s = memory + idx;             d = cb + idx; }
    else if (idx < 4194304) { s = x + (idx - 2097152);      d = cb + idx; }
    else                    { s = pos_emb + (idx - 4194304); d = pb + (idx - 4194304); }
    float4 a = *(const float4*)(s);
    float4 b = *(const float4*)(s + 4);
    u16x8v o;
    o[0] = f2bf(a.x); o[1] = f2bf(a.y); o[2] = f2bf(a.z); o[3] = f2bf(a.w);
    o[4] = f2bf(b.x); o[5] = f2bf(b.y); o[6] = f2bf(b.z); o[7] = f2bf(b.w);
    *(u16x8v*)d = o;
}

// ---------------------------------------------------------------------------
// Fused weight transpose+convert: fp32 [1024][N] -> bf16 [N][1024].
// Flat grid 5120: Wq(1024) | Wkv(2048) | Wrel(1024) | Wo(1024) 32x32 tiles.
// ---------------------------------------------------------------------------
__global__ __launch_bounds__(256) void trans_all(
    const float* __restrict__ Wq, const float* __restrict__ Wkv,
    const float* __restrict__ Wrel, const float* __restrict__ Wo,
    ushort* __restrict__ Wqt, ushort* __restrict__ Wkvt,
    ushort* __restrict__ Wrelt, ushort* __restrict__ Wot)
{
    __shared__ float t[32][33];
    int tb = blockIdx.x;
    const float* src; ushort* dst; int N;
    if (tb < 1024)      { src = Wq;   dst = Wqt;   N = 1024; }
    else if (tb < 3072) { src = Wkv;  dst = Wkvt;  N = 2048; tb -= 1024; }
    else if (tb < 4096) { src = Wrel; dst = Wrelt; N = 1024; tb -= 3072; }
    else                { src = Wo;   dst = Wot;   N = 1024; tb -= 4096; }
    int k0 = (tb & 31) * 32, n0 = (tb >> 5) * 32;
    int tid = threadIdx.x;
    int r = tid >> 3, c4 = (tid & 7) * 4;
    float4 v = *(const float4*)(src + (size_t)(k0 + r) * N + n0 + c4);
    t[r][c4 + 0] = v.x; t[r][c4 + 1] = v.y; t[r][c4 + 2] = v.z; t[r][c4 + 3] = v.w;
    __syncthreads();
    u16x4v o;
    o[0] = f2bf(t[c4 + 0][r]); o[1] = f2bf(t[c4 + 1][r]);
    o[2] = f2bf(t[c4 + 2][r]); o[3] = f2bf(t[c4 + 3][r]);
    *(u16x4v*)(dst + (size_t)(n0 + r) * 1024 + k0 + c4) = o;
}

// ---------------------------------------------------------------------------
// 64x64-tile bf16 MFMA GEMM (512 blocks for q/o: full-machine occupancy).
// omode 0: q -> qu=(+bu), qv=(+bv), layout [bh][L][64]
// omode 3: outF[m][n] = acc + resid  (fp32)
// ---------------------------------------------------------------------------
__global__ __launch_bounds__(256) void gemm_bf16(
    const ushort* __restrict__ A, const ushort* __restrict__ Wt,
    int omode,
    const float* __restrict__ bu, const float* __restrict__ bv,
    ushort* __restrict__ outA, ushort* __restrict__ outB,
    const float* __restrict__ resid, float* __restrict__ outF)
{
    __shared__ ushort Al[64][40];
    __shared__ ushort Bl[64][40];
    int tid = threadIdx.x;
    int M0 = blockIdx.x * 64, N0 = blockIdx.y * 64;
    int wid = tid >> 6, lane = tid & 63, quad = lane >> 4, jl = lane & 15;
    int m0w = (wid >> 1) * 32, n0w = (wid & 1) * 32;
    int sr = tid >> 2, sc = (tid & 3) * 8;

    f32x4 acc[2][2];
    #pragma unroll
    for (int i = 0; i < 2; ++i)
        #pragma unroll
        for (int j = 0; j < 2; ++j) acc[i][j] = (f32x4){0.f, 0.f, 0.f, 0.f};

    for (int k0 = 0; k0 < 1024; k0 += 32) {
        *(u16x8v*)&Al[sr][sc] = *(const u16x8v*)(A  + (size_t)(M0 + sr) * 1024 + k0 + sc);
        *(u16x8v*)&Bl[sr][sc] = *(const u16x8v*)(Wt + (size_t)(N0 + sr) * 1024 + k0 + sc);
        __syncthreads();
        bf16x8 a0 = *(const bf16x8*)&Al[m0w + jl][quad * 8];
        bf16x8 a1 = *(const bf16x8*)&Al[m0w + 16 + jl][quad * 8];
        bf16x8 b0 = *(const bf16x8*)&Bl[n0w + jl][quad * 8];
        bf16x8 b1 = *(const bf16x8*)&Bl[n0w + 16 + jl][quad * 8];
        acc[0][0] = MFMA16(a0, b0, acc[0][0]);
        acc[0][1] = MFMA16(a0, b1, acc[0][1]);
        acc[1][0] = MFMA16(a1, b0, acc[1][0]);
        acc[1][1] = MFMA16(a1, b1, acc[1][1]);
        __syncthreads();
    }

    #pragma unroll
    for (int ms = 0; ms < 2; ++ms)
        #pragma unroll
        for (int ns = 0; ns < 2; ++ns)
            #pragma unroll
            for (int r = 0; r < 4; ++r) {
                int gm = M0 + m0w + 16 * ms + quad * 4 + r;
                int gn = N0 + n0w + 16 * ns + jl;
                float v = acc[ms][ns][r];
                if (omode == 0) {
                    int l = gm >> 1, b = gm & 1;
                    int h = gn >> 6, d = gn & 63;
                    size_t o = ((size_t)((b << 4) | h) * 1024 + l) * 64 + d;
                    outA[o] = f2bf(v + bu[gn]);
                    outB[o] = f2bf(v + bv[gn]);
                } else {
                    outF[(size_t)gm * 1024 + gn] = v + resid[(size_t)gm * 1024 + gn];
                }
            }
}

// ---------------------------------------------------------------------------
// 128x128-tile bf16 MFMA GEMM (m97 structure) for kv / r projections.
// omode 1: kv -> n<1024: k row-major [bh][T][64]; else v TRANSPOSED [bh][64][T]
// omode 2: r -> [bh][T][64]
// ---------------------------------------------------------------------------
__global__ __launch_bounds__(256) void gemm128(
    const ushort* __restrict__ A, const ushort* __restrict__ Wt,
    int omode,
    ushort* __restrict__ outA, ushort* __restrict__ outB)
{
    __shared__ ushort Al[128 * 32];
    __shared__ ushort Bl[128 * 32];
    int tid = threadIdx.x;
    int wid = tid >> 6, lane = tid & 63, quad = lane >> 4, jl = lane & 15;
    int wr = wid >> 1, wc = wid & 1;
    int M0 = blockIdx.x * 128, N0 = blockIdx.y * 128;

    int srow = lane >> 2;
    int scol = (lane & 3) * 8;

    f32x4 acc[4][4];
    #pragma unroll
    for (int i = 0; i < 4; ++i)
        #pragma unroll
        for (int j = 0; j < 4; ++j) acc[i][j] = (f32x4){0.f, 0.f, 0.f, 0.f};

    for (int k0 = 0; k0 < 1024; k0 += 32) {
        #pragma unroll
        for (int c = 0; c < 2; ++c) {
            int r = wid * 32 + c * 16 + srow;
            gl_lds16(A  + (size_t)(M0 + r) * 1024 + k0 + scol,
                     Al + wid * 1024 + c * 512);
            gl_lds16(Wt + (size_t)(N0 + r) * 1024 + k0 + scol,
                     Bl + wid * 1024 + c * 512);
        }
        __syncthreads();
        bf16x8 af[4], bfr[4];
        #pragma unroll
        for (int mt = 0; mt < 4; ++mt)
            af[mt] = *(const bf16x8*)&Al[(wr * 64 + mt * 16 + jl) * 32 + quad * 8];
        #pragma unroll
        for (int nt = 0; nt < 4; ++nt)
            bfr[nt] = *(const bf16x8*)&Bl[(wc * 64 + nt * 16 + jl) * 32 + quad * 8];
        #pragma unroll
        for (int mt = 0; mt < 4; ++mt)
            #pragma unroll
            for (int nt = 0; nt < 4; ++nt)
                acc[mt][nt] = MFMA16(af[mt], bfr[nt], acc[mt][nt]);
        __syncthreads();
    }

    #pragma unroll
    for (int mt = 0; mt < 4; ++mt)
        #pragma unroll
        for (int nt = 0; nt < 4; ++nt)
            #pragma unroll
            for (int r = 0; r < 4; ++r) {
                int gm = M0 + wr * 64 + mt * 16 + quad * 4 + r;
                int gn = N0 + wc * 64 + nt * 16 + jl;
                float v = acc[mt][nt][r];
                int t = gm >> 1, b = gm & 1;
                if (omode == 1) {
                    int nn = gn & 1023;
                    int h = nn >> 6, d = nn & 63;
                    if (gn < 1024)
                        outA[((size_t)((b << 4) | h) * 2048 + t) * 64 + d] = f2bf(v);
                    else
                        outB[((size_t)((b << 4) | h) * 64 + d) * 2048 + t] = f2bf(v);
                } else {
                    int h = gn >> 6, d = gn & 63;
                    outA[((size_t)((b << 4) | h) * 2048 + t) * 64 + d] = f2bf(v);
                }
            }
}

// ---------------------------------------------------------------------------
// Barrier-free single-pass attention with L1-sharing decode.
// Block = 4 waves on the SAME bh, SAME seg, ADJACENT i-tiles (it = 4*grp+wid,
// so nc = 17+grp is block-uniform and all 4 waves walk the SAME chunk list):
// K and V fragment addresses are identical across the block's waves -> L1
// hits after the lead wave; R windows overlap 4/5. XCD-bh binding kept.
// ---------------------------------------------------------------------------
__global__ __launch_bounds__(256) void attn_fused7(
    const ushort* __restrict__ qu, const ushort* __restrict__ qv,
    const ushort* __restrict__ kb, const ushort* __restrict__ Vt,
    const ushort* __restrict__ rb,
    float* __restrict__ Opart, float* __restrict__ lpart,
    ushort* __restrict__ AMw)
{
    __shared__ ushort Pl[4][2][16][76];

    int tid = threadIdx.x, wid = tid >> 6, lane = tid & 63;
    int quad = lane >> 4, jl = lane & 15;

    // decode: 2048 blocks; xcd owns bh group of 4 (L2); block shares bh+seg
    int lin  = blockIdx.x;
    int xcd  = lin & 7;
    int rest = lin >> 3;               // 0..255
    int bh   = (xcd << 2) | (rest & 3);
    int grp  = (rest >> 2) & 15;       // 64-row group
    int seg  = rest >> 6;              // 0..3
    int it   = grp * 4 + wid;
    int i0w  = it * 16;
    int nc   = 17 + grp;               // == 17 + (it>>2), block-uniform
    int cb_  = seg * nc / 4;
    int ce_  = (seg + 1) * nc / 4;
    int irow = i0w + quad * 4;

    const ushort* kp  = kb + (size_t)bh * 2048 * 64;
    const ushort* vtp = Vt + (size_t)bh * 64 * 2048;
    const ushort* rp  = rb + (size_t)bh * 2048 * 64;
    const ushort* qup = qu + (size_t)bh * 1024 * 64;
    const ushort* qvp = qv + (size_t)bh * 1024 * 64;

    bf16x8 quA[2], qvA[2];
    quA[0] = *(const bf16x8*)(qup + (size_t)(i0w + jl) * 64 + quad * 8);
    quA[1] = *(const bf16x8*)(qup + (size_t)(i0w + jl) * 64 + 32 + quad * 8);
    qvA[0] = *(const bf16x8*)(qvp + (size_t)(i0w + jl) * 64 + quad * 8);
    qvA[1] = *(const bf16x8*)(qvp + (size_t)(i0w + jl) * 64 + 32 + quad * 8);

    f32x4 z = (f32x4){0.f, 0.f, 0.f, 0.f};
    f32x4 oacc[4];
    #pragma unroll
    for (int nt = 0; nt < 4; ++nt) oacc[nt] = z;
    float lsum[4] = {0.f, 0.f, 0.f, 0.f};

    for (int c = cb_; c < ce_; ++c) {
        int j0 = c * 64;
        int par = c & 1;
        // ---- AC: 4 column-subtiles of 16 ----
        f32x4 ac[4];
        #pragma unroll
        for (int su = 0; su < 4; ++su) {
            const ushort* krow = kp + (size_t)(j0 + su * 16 + jl) * 64;
            bf16x8 k0 = *(const bf16x8*)(krow + quad * 8);
            bf16x8 k1 = *(const bf16x8*)(krow + 32 + quad * 8);
            f32x4 t = MFMA16(quA[0], k0, z);
            ac[su] = MFMA16(quA[1], k1, t);
        }
        // ---- BD windows: 5 n-tiles covering r-rows d0 .. d0+79 ----
        int d0 = 1008 + j0 - i0w;
        f32x4 bt[5];
        #pragma unroll
        for (int nt = 0; nt < 5; ++nt) {
            int rr = d0 + nt * 16 + jl;
            rr = min(max(rr, 0), 2047);
            const ushort* rrow = rp + (size_t)rr * 64;
            bf16x8 r0 = *(const bf16x8*)(rrow + quad * 8);
            bf16x8 r1 = *(const bf16x8*)(rrow + 32 + quad * 8);
            f32x4 t = MFMA16(qvA[0], r0, z);
            bt[nt] = MFMA16(qvA[1], r1, t);
        }
        // ---- diagonal extraction, exp, stage P ----
        #pragma unroll
        for (int r = 0; r < 4; ++r) {
            int ii = quad * 4 + r;
            int src = (quad << 4) | ((jl + 15 - ii) & 15);
            float bs[5];
            #pragma unroll
            for (int nt = 0; nt < 5; ++nt) bs[nt] = __shfl(bt[nt][r], src);
            bool hi = (jl > ii);
            #pragma unroll
            for (int su = 0; su < 4; ++su) {
                float bd = hi ? bs[su + 1] : bs[su];
                float sv = (ac[su][r] + bd) * SCALE_;
                int j = j0 + su * 16 + jl;
                float p = (j <= irow + r + M_) ? __expf(fminf(sv, 60.f)) : 0.f;
                lsum[r] += p;
                Pl[wid][par][ii][su * 16 + jl] = f2bf(p);
            }
        }
        asm volatile("s_waitcnt lgkmcnt(0)" ::: "memory");
        bf16x8 pA0 = *(const bf16x8*)&Pl[wid][par][jl][quad * 8];
        bf16x8 pA1 = *(const bf16x8*)&Pl[wid][par][jl][32 + quad * 8];
        // ---- plane write to [i][bh][j]: 16 rows x 64 cols, NT ----
        {
            int prow = lane >> 2, pcol = (lane & 3) * 16;
            u16x8v pv0 = *(const u16x8v*)&Pl[wid][par][prow][pcol];
            u16x8v pv1 = *(const u16x8v*)&Pl[wid][par][prow][pcol + 8];
            ushort* dst = AMw + ((size_t)(i0w + prow) * 32 + bh) * 2048 + j0 + pcol;
            __builtin_nontemporal_store(pv0, (u16x8v*)dst);
            __builtin_nontemporal_store(pv1, (u16x8v*)(dst + 8));
        }
        // ---- PV: 64 keys -> 2 MFMAs per 16-col d-tile ----
        #pragma unroll
        for (int nt = 0; nt < 4; ++nt) {
            const ushort* vrow = vtp + (size_t)(nt * 16 + jl) * 2048 + j0;
            bf16x8 vB0 = *(const bf16x8*)(vrow + quad * 8);
            bf16x8 vB1 = *(const bf16x8*)(vrow + 32 + quad * 8);
            oacc[nt] = MFMA16(pA0, vB0, oacc[nt]);
            oacc[nt] = MFMA16(pA1, vB1, oacc[nt]);
        }
    }

    // ---- epilogue: combine partials ----
    #pragma unroll
    for (int r = 0; r < 4; ++r) {
        #pragma unroll
        for (int off = 1; off < 16; off <<= 1) lsum[r] += __shfl_xor(lsum[r], off);
        if (jl == 0) atomicAdd(&lpart[(size_t)bh * 1024 + irow + r], lsum[r]);
    }
    #pragma unroll
    for (int nt = 0; nt < 4; ++nt)
        #pragma unroll
        for (int r = 0; r < 4; ++r)
            atomicAdd(&Opart[((size_t)bh * 1024 + irow + r) * 64 + nt * 16 + jl],
                      oacc[nt][r]);
}

// ---------------------------------------------------------------------------
// Combine O partials: O = Opart / l -> bf16 row-major [L*B][1024];
// emit linvs[i][bh] = (1/l)/32 for am_reduce.
// ---------------------------------------------------------------------------
__global__ __launch_bounds__(256) void o_combine(
    const float* __restrict__ Opart, const float* __restrict__ lpart,
    ushort* __restrict__ OvecB, float* __restrict__ linvs)
{
    int idx8 = (blockIdx.x * 256 + threadIdx.x) * 8;
    int bh = idx8 >> 16;
    int rem = idx8 & 65535;
    int i = rem >> 6, d0 = rem & 63;
    float linv = 1.f / lpart[(size_t)bh * 1024 + i];
    float4 a = *(const float4*)(Opart + idx8);
    float4 b4 = *(const float4*)(Opart + idx8 + 4);
    u16x8v o;
    o[0] = f2bf(a.x * linv);  o[1] = f2bf(a.y * linv);
    o[2] = f2bf(a.z * linv);  o[3] = f2bf(a.w * linv);
    o[4] = f2bf(b4.x * linv); o[5] = f2bf(b4.y * linv);
    o[6] = f2bf(b4.z * linv); o[7] = f2bf(b4.w * linv);
    int b = bh >> 4, h = bh & 15;
    *(u16x8v*)(OvecB + (size_t)(i * 2 + b) * 1024 + h * 64 + d0) = o;
    if (d0 == 0) linvs[(size_t)i * 32 + bh] = linv * 0.03125f;
}

// ---------------------------------------------------------------------------
// AM[i][j] = sum_bh plane[i][bh][j] * linvs[i][bh], re-masked.
// One block per row i: fully contiguous 128 KB stream per block.
// ---------------------------------------------------------------------------
__global__ __launch_bounds__(256) void am_reduce(const ushort* __restrict__ AMw,
                                                 const float* __restrict__ linvs,
                                                 float* __restrict__ AM) {
    __shared__ float lv[32];
    int i = blockIdx.x;
    int tid = threadIdx.x;
    if (tid < 32) lv[tid] = linvs[(size_t)i * 32 + tid];
    __syncthreads();
    int j0 = tid * 8;
    int jmax = i + M_;
    float acc[8];
    #pragma unroll
    for (int e = 0; e < 8; ++e) acc[e] = 0.f;
    if (j0 <= jmax) {
        const ushort* base = AMw + (size_t)i * 65536;
        for (int p = 0; p < 32; ++p) {
            float l = lv[p];
            u16x8v v = __builtin_nontemporal_load(
                (const u16x8v*)(base + (size_t)p * 2048 + j0));
            #pragma unroll
            for (int e = 0; e < 8; ++e) acc[e] += bf2f(v[e]) * l;
        }
    }
    float4 o0, o1;
    o0.x = (j0 + 0 <= jmax) ? acc[0] : 0.f;
    o0.y = (j0 + 1 <= jmax) ? acc[1] : 0.f;
    o0.z = (j0 + 2 <= jmax) ? acc[2] : 0.f;
    o0.w = (j0 + 3 <= jmax) ? acc[3] : 0.f;
    o1.x = (j0 + 4 <= jmax) ? acc[4] : 0.f;
    o1.y = (j0 + 5 <= jmax) ? acc[5] : 0.f;
    o1.z = (j0 + 6 <= jmax) ? acc[6] : 0.f;
    o1.w = (j0 + 7 <= jmax) ? acc[7] : 0.f;
    *(float4*)(AM + (size_t)i * 2048 + j0) = o0;
    *(float4*)(AM + (size_t)i * 2048 + j0 + 4) = o1;
}

// ---------------------------------------------------------------------------
// LayerNorm over D=1024, one block per row
// ---------------------------------------------------------------------------
__global__ __launch_bounds__(256) void ln_kernel(
    const float* __restrict__ hbuf,
    const float* __restrict__ gamma, const float* __restrict__ beta,
    float* __restrict__ out)
{
    __shared__ float rs[4], rss[4];
    int row = blockIdx.x;
    int tid = threadIdx.x;
    const float* hp = hbuf + (size_t)row * 1024;
    float4 h4 = *(const float4*)(hp + (tid << 2));
    float s = h4.x + h4.y + h4.z + h4.w;
    float ss = h4.x * h4.x + h4.y * h4.y + h4.z * h4.z + h4.w * h4.w;
    #pragma unroll
    for (int o = 32; o > 0; o >>= 1) {
        s  += __shfl_down(s, o);
        ss += __shfl_down(ss, o);
    }
    if ((tid & 63) == 0) { rs[tid >> 6] = s; rss[tid >> 6] = ss; }
    __syncthreads();
    float tot  = rs[0] + rs[1] + rs[2] + rs[3];
    float tots = rss[0] + rss[1] + rss[2] + rss[3];
    float mu = tot * (1.f / 1024.f);
    float var = tots * (1.f / 1024.f) - mu * mu;
    float rstd = rsqrtf(var + 1e-5f);
    float4 g4 = *(const float4*)(gamma + (tid << 2));
    float4 b4 = *(const float4*)(beta + (tid << 2));
    float4 o4;
    o4.x = (h4.x - mu) * rstd * g4.x + b4.x;
    o4.y = (h4.y - mu) * rstd * g4.y + b4.y;
    o4.z = (h4.z - mu) * rstd * g4.z + b4.z;
    o4.w = (h4.w - mu) * rstd * g4.w + b4.w;
    *(float4*)(out + (size_t)row * 1024 + (tid << 2)) = o4;
}

extern "C" void kernel_launch(void* const* d_in, const int* in_sizes, int n_in,
                              void* d_out, int out_size, void* d_ws, size_t ws_size,
                              hipStream_t stream) {
    const float* x       = (const float*)d_in[0];
    const float* pos_emb = (const float*)d_in[1];
    const float* memory  = (const float*)d_in[2];
    const float* bu      = (const float*)d_in[3];
    const float* bv      = (const float*)d_in[4];
    const float* Wq      = (const float*)d_in[6];
    const float* Wkv     = (const float*)d_in[7];
    const float* Wrel    = (const float*)d_in[8];
    const float* Wo      = (const float*)d_in[9];
    const float* gamma   = (const float*)d_in[10];
    const float* beta    = (const float*)d_in[11];

    float* out = (float*)d_out;
    float* AM  = out + (size_t)2097152;       // attn_matrix [L][T]

    ushort* cb    = (ushort*)d_ws;            // [4096][1024]
    ushort* pb    = cb    + 4194304;          // [4096][1024]
    ushort* Wqt   = pb    + 4194304;          // [1024][1024]
    ushort* Wkvt  = Wqt   + 1048576;          // [2048][1024]
    ushort* Wrelt = Wkvt  + 2097152;          // [1024][1024]
    ushort* Wot   = Wrelt + 1048576;          // [1024][1024]
    ushort* quB   = Wot   + 1048576;          // [32][1024][64]
    ushort* qvB   = quB   + 2097152;
    ushort* kbB   = qvB   + 2097152;          // [32][2048][64]
    ushort* VtB   = kbB   + 4194304;          // [32][64][2048]
    ushort* rbB   = VtB   + 4194304;          // [32][2048][64]
    ushort* OvecB = rbB   + 4194304;          // [2048][1024]
    float*  hbuf  = (float*)(OvecB + 2097152);// [2048][1024] fp32
    float*  Opart = hbuf  + 2097152;          // [32][1024][64] fp32
    float*  lpart = Opart + 2097152;          // [32][1024] fp32
    float*  linvs = lpart + 32768;            // [1024][32] fp32
    ushort* AMw   = (ushort*)(linvs + 32768); // [1024][32][2048] bf16 (128 MB)

    dim3 blk(256);
    // fused converts
    cvt_all<<<4096, blk, 0, stream>>>(memory, x, pos_emb, cb, pb);
    trans_all<<<5120, blk, 0, stream>>>(Wq, Wkv, Wrel, Wo, Wqt, Wkvt, Wrelt, Wot);
    hipMemsetAsync(Opart, 0, (size_t)2097152 * sizeof(float), stream);
    hipMemsetAsync(lpart, 0, (size_t)32768 * sizeof(float), stream);

    // projections
    gemm_bf16<<<dim3(32, 16), blk, 0, stream>>>(cb + 2097152, Wqt, 0, bu, bv,
                                                quB, qvB, nullptr, nullptr);
    gemm128<<<dim3(32, 16), blk, 0, stream>>>(cb, Wkvt, 1, kbB, VtB);
    gemm128<<<dim3(32, 8), blk, 0, stream>>>(pb, Wrelt, 2, rbB, nullptr);
    // attention (barrier-free, L1-sharing block decode, XCD-bh binding)
    attn_fused7<<<dim3(2048), blk, 0, stream>>>(quB, qvB, kbB, VtB, rbB,
                                                Opart, lpart, AMw);
    // combine partials -> OvecB + linvs
    o_combine<<<1024, blk, 0, stream>>>(Opart, lpart, OvecB, linvs);
    // output projection + residual
    gemm_bf16<<<dim3(32, 16), blk, 0, stream>>>(OvecB, Wot, 3, nullptr, nullptr,
                                                nullptr, nullptr, x, hbuf);
    // layernorm
    ln_kernel<<<2048, blk, 0, stream>>>(hbuf, gamma, beta, out);
    // attn_matrix reduction (streaming)
    am_reduce<<<1024, blk, 0, stream>>>(AMw, linvs, AM);
}

// Round 9
// 404.041 us; speedup vs baseline: 1.1701x; 1.0374x over previous
//
#include <hip/hip_runtime.h>
#include <math.h>
#include <stdint.h>

#define L_  1024
#define B_  2
#define D_  1024
#define H_  16
#define DH_ 64
#define M_  1024
#define T_  2048
#define SCALE_ 0.125f

typedef unsigned short ushort;
typedef short bf16x8 __attribute__((ext_vector_type(8)));
typedef float f32x4 __attribute__((ext_vector_type(4)));
typedef unsigned short u16x4v __attribute__((ext_vector_type(4)));
typedef unsigned short u16x8v __attribute__((ext_vector_type(8)));

#define MFMA16(a,b,c) __builtin_amdgcn_mfma_f32_16x16x32_bf16(a,b,c,0,0,0)

static __device__ __forceinline__ ushort f2bf(float x) {
    uint32_t u = __float_as_uint(x);
    uint32_t r = (u + 0x7FFFu + ((u >> 16) & 1u)) >> 16;
    return (ushort)r;
}
static __device__ __forceinline__ float bf2f(ushort h) {
    return __uint_as_float(((uint32_t)h) << 16);
}
// async global->LDS, 16B per lane; LDS dest = wave-uniform base + lane*16
static __device__ __forceinline__ void gl_lds16(const ushort* g, ushort* l) {
    __builtin_amdgcn_global_load_lds(
        (const __attribute__((address_space(1))) void*)g,
        (__attribute__((address_space(3))) void*)l, 16, 0, 0);
}

// ---------------------------------------------------------------------------
// Fused prep: fp32->bf16 converts (blocks 0..4095) + weight transposes
// (blocks 4096..9215; 32x32 tiles over Wq|Wkv|Wrel|Wo).
// ---------------------------------------------------------------------------
__global__ __launch_bounds__(256) void prep(
    const float* __restrict__ memory, const float* __restrict__ x,
    const float* __restrict__ pos_emb,
    const float* __restrict__ Wq, const float* __restrict__ Wkv,
    const float* __restrict__ Wrel, const float* __restrict__ Wo,
    ushort* __restrict__ cb, ushort* __restrict__ pb,
    ushort* __restrict__ Wqt, ushort* __restrict__ Wkvt,
    ushort* __restrict__ Wrelt, ushort* __restrict__ Wot)
{
    __shared__ float t[32][33];
    int tid = threadIdx.x;
    if (blockIdx.x < 4096) {
        int idx = (blockIdx.x * 256 + tid) * 8;
        const float* s;
        ushort* d;
        if (idx < 2097152)      { s = memory + idx;              d = cb + idx; }
        else if (idx < 4194304) { s = x + (idx - 2097152);       d = cb + idx; }
        else                    { s = pos_emb + (idx - 4194304); d = pb + (idx - 4194304); }
        float4 a = *(const float4*)(s);
        float4 b = *(const float4*)(s + 4);
        u16x8v o;
        o[0] = f2bf(a.x); o[1] = f2bf(a.y); o[2] = f2bf(a.z); o[3] = f2bf(a.w);
        o[4] = f2bf(b.x); o[5] = f2bf(b.y); o[6] = f2bf(b.z); o[7] = f2bf(b.w);
        *(u16x8v*)d = o;
        return;
    }
    int tb = blockIdx.x - 4096;
    const float* src; ushort* dst; int N;
    if (tb < 1024)      { src = Wq;   dst = Wqt;   N = 1024; }
    else if (tb < 3072) { src = Wkv;  dst = Wkvt;  N = 2048; tb -= 1024; }
    else if (tb < 4096) { src = Wrel; dst = Wrelt; N = 1024; tb -= 3072; }
    else                { src = Wo;   dst = Wot;   N = 1024; tb -= 4096; }
    int k0 = (tb & 31) * 32, n0 = (tb >> 5) * 32;
    int r = tid >> 3, c4 = (tid & 7) * 4;
    float4 v = *(const float4*)(src + (size_t)(k0 + r) * N + n0 + c4);
    t[r][c4 + 0] = v.x; t[r][c4 + 1] = v.y; t[r][c4 + 2] = v.z; t[r][c4 + 3] = v.w;
    __syncthreads();
    u16x4v o;
    o[0] = f2bf(t[c4 + 0][r]); o[1] = f2bf(t[c4 + 1][r]);
    o[2] = f2bf(t[c4 + 2][r]); o[3] = f2bf(t[c4 + 3][r]);
    *(u16x4v*)(dst + (size_t)(n0 + r) * 1024 + k0 + c4) = o;
}

// ---------------------------------------------------------------------------
// 64x64-tile bf16 MFMA GEMM (512 blocks for q/o: full-machine occupancy).
// omode 0: q -> qu=(+bu), qv=(+bv), layout [bh][L][64]
// omode 3: outF[m][n] = acc + resid  (fp32)
// ---------------------------------------------------------------------------
__global__ __launch_bounds__(256) void gemm_bf16(
    const ushort* __restrict__ A, const ushort* __restrict__ Wt,
    int omode,
    const float* __restrict__ bu, const float* __restrict__ bv,
    ushort* __restrict__ outA, ushort* __restrict__ outB,
    const float* __restrict__ resid, float* __restrict__ outF)
{
    __shared__ ushort Al[64][40];
    __shared__ ushort Bl[64][40];
    int tid = threadIdx.x;
    int M0 = blockIdx.x * 64, N0 = blockIdx.y * 64;
    int wid = tid >> 6, lane = tid & 63, quad = lane >> 4, jl = lane & 15;
    int m0w = (wid >> 1) * 32, n0w = (wid & 1) * 32;
    int sr = tid >> 2, sc = (tid & 3) * 8;

    f32x4 acc[2][2];
    #pragma unroll
    for (int i = 0; i < 2; ++i)
        #pragma unroll
        for (int j = 0; j < 2; ++j) acc[i][j] = (f32x4){0.f, 0.f, 0.f, 0.f};

    for (int k0 = 0; k0 < 1024; k0 += 32) {
        *(u16x8v*)&Al[sr][sc] = *(const u16x8v*)(A  + (size_t)(M0 + sr) * 1024 + k0 + sc);
        *(u16x8v*)&Bl[sr][sc] = *(const u16x8v*)(Wt + (size_t)(N0 + sr) * 1024 + k0 + sc);
        __syncthreads();
        bf16x8 a0 = *(const bf16x8*)&Al[m0w + jl][quad * 8];
        bf16x8 a1 = *(const bf16x8*)&Al[m0w + 16 + jl][quad * 8];
        bf16x8 b0 = *(const bf16x8*)&Bl[n0w + jl][quad * 8];
        bf16x8 b1 = *(const bf16x8*)&Bl[n0w + 16 + jl][quad * 8];
        acc[0][0] = MFMA16(a0, b0, acc[0][0]);
        acc[0][1] = MFMA16(a0, b1, acc[0][1]);
        acc[1][0] = MFMA16(a1, b0, acc[1][0]);
        acc[1][1] = MFMA16(a1, b1, acc[1][1]);
        __syncthreads();
    }

    #pragma unroll
    for (int ms = 0; ms < 2; ++ms)
        #pragma unroll
        for (int ns = 0; ns < 2; ++ns)
            #pragma unroll
            for (int r = 0; r < 4; ++r) {
                int gm = M0 + m0w + 16 * ms + quad * 4 + r;
                int gn = N0 + n0w + 16 * ns + jl;
                float v = acc[ms][ns][r];
                if (omode == 0) {
                    int l = gm >> 1, b = gm & 1;
                    int h = gn >> 6, d = gn & 63;
                    size_t o = ((size_t)((b << 4) | h) * 1024 + l) * 64 + d;
                    outA[o] = f2bf(v + bu[gn]);
                    outB[o] = f2bf(v + bv[gn]);
                } else {
                    outF[(size_t)gm * 1024 + gn] = v + resid[(size_t)gm * 1024 + gn];
                }
            }
}

// ---------------------------------------------------------------------------
// 128x128-tile bf16 MFMA GEMM (m97 structure) for kv / r projections.
// omode 1: kv -> n<1024: k row-major [bh][T][64]; else v TRANSPOSED [bh][64][T]
// omode 2: r -> [bh][T][64]
// ---------------------------------------------------------------------------
__global__ __launch_bounds__(256) void gemm128(
    const ushort* __restrict__ A, const ushort* __restrict__ Wt,
    int omode,
    ushort* __restrict__ outA, ushort* __restrict__ outB)
{
    __shared__ ushort Al[128 * 32];
    __shared__ ushort Bl[128 * 32];
    int tid = threadIdx.x;
    int wid = tid >> 6, lane = tid & 63, quad = lane >> 4, jl = lane & 15;
    int wr = wid >> 1, wc = wid & 1;
    int M0 = blockIdx.x * 128, N0 = blockIdx.y * 128;

    int srow = lane >> 2;
    int scol = (lane & 3) * 8;

    f32x4 acc[4][4];
    #pragma unroll
    for (int i = 0; i < 4; ++i)
        #pragma unroll
        for (int j = 0; j < 4; ++j) acc[i][j] = (f32x4){0.f, 0.f, 0.f, 0.f};

    for (int k0 = 0; k0 < 1024; k0 += 32) {
        #pragma unroll
        for (int c = 0; c < 2; ++c) {
            int r = wid * 32 + c * 16 + srow;
            gl_lds16(A  + (size_t)(M0 + r) * 1024 + k0 + scol,
                     Al + wid * 1024 + c * 512);
            gl_lds16(Wt + (size_t)(N0 + r) * 1024 + k0 + scol,
                     Bl + wid * 1024 + c * 512);
        }
        __syncthreads();
        bf16x8 af[4], bfr[4];
        #pragma unroll
        for (int mt = 0; mt < 4; ++mt)
            af[mt] = *(const bf16x8*)&Al[(wr * 64 + mt * 16 + jl) * 32 + quad * 8];
        #pragma unroll
        for (int nt = 0; nt < 4; ++nt)
            bfr[nt] = *(const bf16x8*)&Bl[(wc * 64 + nt * 16 + jl) * 32 + quad * 8];
        #pragma unroll
        for (int mt = 0; mt < 4; ++mt)
            #pragma unroll
            for (int nt = 0; nt < 4; ++nt)
                acc[mt][nt] = MFMA16(af[mt], bfr[nt], acc[mt][nt]);
        __syncthreads();
    }

    #pragma unroll
    for (int mt = 0; mt < 4; ++mt)
        #pragma unroll
        for (int nt = 0; nt < 4; ++nt)
            #pragma unroll
            for (int r = 0; r < 4; ++r) {
                int gm = M0 + wr * 64 + mt * 16 + quad * 4 + r;
                int gn = N0 + wc * 64 + nt * 16 + jl;
                float v = acc[mt][nt][r];
                int t = gm >> 1, b = gm & 1;
                if (omode == 1) {
                    int nn = gn & 1023;
                    int h = nn >> 6, d = nn & 63;
                    if (gn < 1024)
                        outA[((size_t)((b << 4) | h) * 2048 + t) * 64 + d] = f2bf(v);
                    else
                        outB[((size_t)((b << 4) | h) * 64 + d) * 2048 + t] = f2bf(v);
                } else {
                    int h = gn >> 6, d = gn & 63;
                    outA[((size_t)((b << 4) | h) * 2048 + t) * 64 + d] = f2bf(v);
                }
            }
}

// ---------------------------------------------------------------------------
// Score kernel: AC+BD -> p = exp(s*scale) -> NT store to planes [i][bh][j].
// ZERO LDS / fences / barriers; only loop-carried dep is lsum + stores.
// Block = 4 waves, same bh+seg, adjacent i-tiles (L1 sharing); XCD-bh binding.
// ---------------------------------------------------------------------------
__global__ __launch_bounds__(256) void attn_score(
    const ushort* __restrict__ qu, const ushort* __restrict__ qv,
    const ushort* __restrict__ kb, const ushort* __restrict__ rb,
    float* __restrict__ lpart, ushort* __restrict__ AMw)
{
    int tid = threadIdx.x, wid = tid >> 6, lane = tid & 63;
    int quad = lane >> 4, jl = lane & 15;

    int lin  = blockIdx.x;
    int xcd  = lin & 7;
    int rest = lin >> 3;               // 0..255
    int bh   = (xcd << 2) | (rest & 3);
    int grp  = (rest >> 2) & 15;       // 64-row group
    int seg  = rest >> 6;              // 0..3
    int it   = grp * 4 + wid;
    int i0w  = it * 16;
    int nc   = 17 + grp;               // block-uniform
    int cb_  = seg * nc / 4;
    int ce_  = (seg + 1) * nc / 4;
    int irow = i0w + quad * 4;

    const ushort* kp  = kb + (size_t)bh * 2048 * 64;
    const ushort* rp  = rb + (size_t)bh * 2048 * 64;
    const ushort* qup = qu + (size_t)bh * 1024 * 64;
    const ushort* qvp = qv + (size_t)bh * 1024 * 64;

    bf16x8 quA[2], qvA[2];
    quA[0] = *(const bf16x8*)(qup + (size_t)(i0w + jl) * 64 + quad * 8);
    quA[1] = *(const bf16x8*)(qup + (size_t)(i0w + jl) * 64 + 32 + quad * 8);
    qvA[0] = *(const bf16x8*)(qvp + (size_t)(i0w + jl) * 64 + quad * 8);
    qvA[1] = *(const bf16x8*)(qvp + (size_t)(i0w + jl) * 64 + 32 + quad * 8);

    f32x4 z = (f32x4){0.f, 0.f, 0.f, 0.f};
    float lsum[4] = {0.f, 0.f, 0.f, 0.f};

    for (int c = cb_; c < ce_; ++c) {
        int j0 = c * 64;
        // ---- AC: 4 column-subtiles of 16 ----
        f32x4 ac[4];
        #pragma unroll
        for (int su = 0; su < 4; ++su) {
            const ushort* krow = kp + (size_t)(j0 + su * 16 + jl) * 64;
            bf16x8 k0 = *(const bf16x8*)(krow + quad * 8);
            bf16x8 k1 = *(const bf16x8*)(krow + 32 + quad * 8);
            f32x4 t = MFMA16(quA[0], k0, z);
            ac[su] = MFMA16(quA[1], k1, t);
        }
        // ---- BD windows: 5 n-tiles covering r-rows d0 .. d0+79 ----
        int d0 = 1008 + j0 - i0w;
        f32x4 bt[5];
        #pragma unroll
        for (int nt = 0; nt < 5; ++nt) {
            int rr = d0 + nt * 16 + jl;
            rr = min(max(rr, 0), 2047);
            const ushort* rrow = rp + (size_t)rr * 64;
            bf16x8 r0 = *(const bf16x8*)(rrow + quad * 8);
            bf16x8 r1 = *(const bf16x8*)(rrow + 32 + quad * 8);
            f32x4 t = MFMA16(qvA[0], r0, z);
            bt[nt] = MFMA16(qvA[1], r1, t);
        }
        // ---- diagonal extraction, exp, NT store in C-layout ----
        #pragma unroll
        for (int r = 0; r < 4; ++r) {
            int ii = quad * 4 + r;
            int src = (quad << 4) | ((jl + 15 - ii) & 15);
            float bs[5];
            #pragma unroll
            for (int nt = 0; nt < 5; ++nt) bs[nt] = __shfl(bt[nt][r], src);
            bool hi = (jl > ii);
            ushort* prow = AMw + ((size_t)(irow + r) * 32 + bh) * 2048 + j0 + jl;
            #pragma unroll
            for (int su = 0; su < 4; ++su) {
                float bd = hi ? bs[su + 1] : bs[su];
                float sv = (ac[su][r] + bd) * SCALE_;
                int j = j0 + su * 16 + jl;
                float p = (j <= irow + r + M_) ? __expf(fminf(sv, 60.f)) : 0.f;
                lsum[r] += p;
                __builtin_nontemporal_store(f2bf(p), prow + su * 16);
            }
        }
    }

    // ---- epilogue: l partial sums ----
    #pragma unroll
    for (int r = 0; r < 4; ++r) {
        #pragma unroll
        for (int off = 1; off < 16; off <<= 1) lsum[r] += __shfl_xor(lsum[r], off);
        if (jl == 0) atomicAdd(&lpart[(size_t)bh * 1024 + irow + r], lsum[r]);
    }
}

// ---------------------------------------------------------------------------
// PV GEMM: O[bh][i][d] = (1/l_i) * sum_j P[i][bh][j] * V[bh][j][d].
// 64x64 tiles over (i,d); K bounded by the causal/written region 64*(17+mt).
// Epilogue folds o_combine: OvecB bf16 row-major + linvs for am_reduce.
// ---------------------------------------------------------------------------
__global__ __launch_bounds__(256) void pv_gemm(
    const ushort* __restrict__ P, const ushort* __restrict__ Vt,
    const float* __restrict__ lpart,
    ushort* __restrict__ OvecB, float* __restrict__ linvs)
{
    __shared__ ushort Al[64][40];
    __shared__ ushort Bl[64][40];
    int tid = threadIdx.x;
    int lin  = blockIdx.x;             // 512
    int xcd  = lin & 7;
    int rest = lin >> 3;               // 0..63
    int bh   = (xcd << 2) | (rest & 3);
    int mt   = rest >> 2;              // 0..15
    int M0   = mt * 64;
    int wid = tid >> 6, lane = tid & 63, quad = lane >> 4, jl = lane & 15;
    int m0w = (wid >> 1) * 32, n0w = (wid & 1) * 32;
    int sr = tid >> 2, sc = (tid & 3) * 8;

    const ushort* Bp = Vt + (size_t)bh * 64 * 2048;
    int kend = (17 + mt) * 64;

    f32x4 acc[2][2];
    #pragma unroll
    for (int i = 0; i < 2; ++i)
        #pragma unroll
        for (int j = 0; j < 2; ++j) acc[i][j] = (f32x4){0.f, 0.f, 0.f, 0.f};

    for (int k0 = 0; k0 < kend; k0 += 32) {
        *(u16x8v*)&Al[sr][sc] =
            *(const u16x8v*)(P + ((size_t)(M0 + sr) * 32 + bh) * 2048 + k0 + sc);
        *(u16x8v*)&Bl[sr][sc] = *(const u16x8v*)(Bp + (size_t)sr * 2048 + k0 + sc);
        __syncthreads();
        bf16x8 a0 = *(const bf16x8*)&Al[m0w + jl][quad * 8];
        bf16x8 a1 = *(const bf16x8*)&Al[m0w + 16 + jl][quad * 8];
        bf16x8 b0 = *(const bf16x8*)&Bl[n0w + jl][quad * 8];
        bf16x8 b1 = *(const bf16x8*)&Bl[n0w + 16 + jl][quad * 8];
        acc[0][0] = MFMA16(a0, b0, acc[0][0]);
        acc[0][1] = MFMA16(a0, b1, acc[0][1]);
        acc[1][0] = MFMA16(a1, b0, acc[1][0]);
        acc[1][1] = MFMA16(a1, b1, acc[1][1]);
        __syncthreads();
    }

    int b = bh >> 4, h = bh & 15;
    #pragma unroll
    for (int ms = 0; ms < 2; ++ms)
        #pragma unroll
        for (int r = 0; r < 4; ++r) {
            int gi = M0 + m0w + 16 * ms + quad * 4 + r;
            float linv = 1.f / lpart[(size_t)bh * 1024 + gi];
            #pragma unroll
            for (int ns = 0; ns < 2; ++ns) {
                int gd = n0w + 16 * ns + jl;
                OvecB[(size_t)(gi * 2 + b) * 1024 + h * 64 + gd] =
                    f2bf(acc[ms][ns][r] * linv);
            }
            if (n0w == 0 && jl == 0)
                linvs[(size_t)gi * 32 + bh] = linv * 0.03125f;
        }
}

// ---------------------------------------------------------------------------
// AM[i][j] = sum_bh plane[i][bh][j] * linvs[i][bh], re-masked.
// One block per row i: fully contiguous 128 KB stream per block.
// ---------------------------------------------------------------------------
__global__ __launch_bounds__(256) void am_reduce(const ushort* __restrict__ AMw,
                                                 const float* __restrict__ linvs,
                                                 float* __restrict__ AM) {
    __shared__ float lv[32];
    int i = blockIdx.x;
    int tid = threadIdx.x;
    if (tid < 32) lv[tid] = linvs[(size_t)i * 32 + tid];
    __syncthreads();
    int j0 = tid * 8;
    int jmax = i + M_;
    float acc[8];
    #pragma unroll
    for (int e = 0; e < 8; ++e) acc[e] = 0.f;
    if (j0 <= jmax) {
        const ushort* base = AMw + (size_t)i * 65536;
        for (int p = 0; p < 32; ++p) {
            float l = lv[p];
            u16x8v v = __builtin_nontemporal_load(
                (const u16x8v*)(base + (size_t)p * 2048 + j0));
            #pragma unroll
            for (int e = 0; e < 8; ++e) acc[e] += bf2f(v[e]) * l;
        }
    }
    float4 o0, o1;
    o0.x = (j0 + 0 <= jmax) ? acc[0] : 0.f;
    o0.y = (j0 + 1 <= jmax) ? acc[1] : 0.f;
    o0.z = (j0 + 2 <= jmax) ? acc[2] : 0.f;
    o0.w = (j0 + 3 <= jmax) ? acc[3] : 0.f;
    o1.x = (j0 + 4 <= jmax) ? acc[4] : 0.f;
    o1.y = (j0 + 5 <= jmax) ? acc[5] : 0.f;
    o1.z = (j0 + 6 <= jmax) ? acc[6] : 0.f;
    o1.w = (j0 + 7 <= jmax) ? acc[7] : 0.f;
    *(float4*)(AM + (size_t)i * 2048 + j0) = o0;
    *(float4*)(AM + (size_t)i * 2048 + j0 + 4) = o1;
}

// ---------------------------------------------------------------------------
// LayerNorm over D=1024, one block per row
// ---------------------------------------------------------------------------
__global__ __launch_bounds__(256) void ln_kernel(
    const float* __restrict__ hbuf,
    const float* __restrict__ gamma, const float* __restrict__ beta,
    float* __restrict__ out)
{
    __shared__ float rs[4], rss[4];
    int row = blockIdx.x;
    int tid = threadIdx.x;
    const float* hp = hbuf + (size_t)row * 1024;
    float4 h4 = *(const float4*)(hp + (tid << 2));
    float s = h4.x + h4.y + h4.z + h4.w;
    float ss = h4.x * h4.x + h4.y * h4.y + h4.z * h4.z + h4.w * h4.w;
    #pragma unroll
    for (int o = 32; o > 0; o >>= 1) {
        s  += __shfl_down(s, o);
        ss += __shfl_down(ss, o);
    }
    if ((tid & 63) == 0) { rs[tid >> 6] = s; rss[tid >> 6] = ss; }
    __syncthreads();
    float tot  = rs[0] + rs[1] + rs[2] + rs[3];
    float tots = rss[0] + rss[1] + rss[2] + rss[3];
    float mu = tot * (1.f / 1024.f);
    float var = tots * (1.f / 1024.f) - mu * mu;
    float rstd = rsqrtf(var + 1e-5f);
    float4 g4 = *(const float4*)(gamma + (tid << 2));
    float4 b4 = *(const float4*)(beta + (tid << 2));
    float4 o4;
    o4.x = (h4.x - mu) * rstd * g4.x + b4.x;
    o4.y = (h4.y - mu) * rstd * g4.y + b4.y;
    o4.z = (h4.z - mu) * rstd * g4.z + b4.z;
    o4.w = (h4.w - mu) * rstd * g4.w + b4.w;
    *(float4*)(out + (size_t)row * 1024 + (tid << 2)) = o4;
}

extern "C" void kernel_launch(void* const* d_in, const int* in_sizes, int n_in,
                              void* d_out, int out_size, void* d_ws, size_t ws_size,
                              hipStream_t stream) {
    const float* x       = (const float*)d_in[0];
    const float* pos_emb = (const float*)d_in[1];
    const float* memory  = (const float*)d_in[2];
    const float* bu      = (const float*)d_in[3];
    const float* bv      = (const float*)d_in[4];
    const float* Wq      = (const float*)d_in[6];
    const float* Wkv     = (const float*)d_in[7];
    const float* Wrel    = (const float*)d_in[8];
    const float* Wo      = (const float*)d_in[9];
    const float* gamma   = (const float*)d_in[10];
    const float* beta    = (const float*)d_in[11];

    float* out = (float*)d_out;
    float* AM  = out + (size_t)2097152;       // attn_matrix [L][T]

    ushort* cb    = (ushort*)d_ws;            // [4096][1024]
    ushort* pb    = cb    + 4194304;          // [4096][1024]
    ushort* Wqt   = pb    + 4194304;          // [1024][1024]
    ushort* Wkvt  = Wqt   + 1048576;          // [2048][1024]
    ushort* Wrelt = Wkvt  + 2097152;          // [1024][1024]
    ushort* Wot   = Wrelt + 1048576;          // [1024][1024]
    ushort* quB   = Wot   + 1048576;          // [32][1024][64]
    ushort* qvB   = quB   + 2097152;
    ushort* kbB   = qvB   + 2097152;          // [32][2048][64]
    ushort* VtB   = kbB   + 4194304;          // [32][64][2048]
    ushort* rbB   = VtB   + 4194304;          // [32][2048][64]
    ushort* OvecB = rbB   + 4194304;          // [2048][1024]
    float*  hbuf  = (float*)(OvecB + 2097152);// [2048][1024] fp32
    float*  lpart = hbuf  + 2097152;          // [32][1024] fp32
    float*  linvs = lpart + 32768;            // [1024][32] fp32
    ushort* AMw   = (ushort*)(linvs + 32768); // [1024][32][2048] bf16 (128 MB)

    dim3 blk(256);
    // fused converts + weight transposes
    prep<<<9216, blk, 0, stream>>>(memory, x, pos_emb, Wq, Wkv, Wrel, Wo,
                                   cb, pb, Wqt, Wkvt, Wrelt, Wot);
    hipMemsetAsync(lpart, 0, (size_t)32768 * sizeof(float), stream);

    // projections
    gemm_bf16<<<dim3(32, 16), blk, 0, stream>>>(cb + 2097152, Wqt, 0, bu, bv,
                                                quB, qvB, nullptr, nullptr);
    gemm128<<<dim3(32, 16), blk, 0, stream>>>(cb, Wkvt, 1, kbB, VtB);
    gemm128<<<dim3(32, 8), blk, 0, stream>>>(pb, Wrelt, 2, rbB, nullptr);
    // scores -> planes (fence-free, LDS-free)
    attn_score<<<dim3(2048), blk, 0, stream>>>(quB, qvB, kbB, rbB, lpart, AMw);
    // PV as causal-K GEMM; folds o_combine
    pv_gemm<<<dim3(512), blk, 0, stream>>>(AMw, VtB, lpart, OvecB, linvs);
    // output projection + residual
    gemm_bf16<<<dim3(32, 16), blk, 0, stream>>>(OvecB, Wot, 3, nullptr, nullptr,
                                                nullptr, nullptr, x, hbuf);
    // layernorm
    ln_kernel<<<2048, blk, 0, stream>>>(hbuf, gamma, beta, out);
    // attn_matrix reduction (streaming)
    am_reduce<<<1024, blk, 0, stream>>>(AMw, linvs, AM);
}

// Round 10
// 397.936 us; speedup vs baseline: 1.1880x; 1.0153x over previous
//
#include <hip/hip_runtime.h>
#include <math.h>
#include <stdint.h>

#define L_  1024
#define B_  2
#define D_  1024
#define H_  16
#define DH_ 64
#define M_  1024
#define T_  2048
#define SCALE_ 0.125f

typedef unsigned short ushort;
typedef short bf16x8 __attribute__((ext_vector_type(8)));
typedef float f32x4 __attribute__((ext_vector_type(4)));
typedef unsigned short u16x4v __attribute__((ext_vector_type(4)));
typedef unsigned short u16x8v __attribute__((ext_vector_type(8)));

#define MFMA16(a,b,c) __builtin_amdgcn_mfma_f32_16x16x32_bf16(a,b,c,0,0,0)

static __device__ __forceinline__ ushort f2bf(float x) {
    uint32_t u = __float_as_uint(x);
    uint32_t r = (u + 0x7FFFu + ((u >> 16) & 1u)) >> 16;
    return (ushort)r;
}
static __device__ __forceinline__ float bf2f(ushort h) {
    return __uint_as_float(((uint32_t)h) << 16);
}

// ---------------------------------------------------------------------------
// Fused prep: fp32->bf16 converts (blocks 0..4095) + weight transposes
// (blocks 4096..9215; 32x32 tiles over Wq|Wkv|Wrel|Wo).
// ---------------------------------------------------------------------------
__global__ __launch_bounds__(256) void prep(
    const float* __restrict__ memory, const float* __restrict__ x,
    const float* __restrict__ pos_emb,
    const float* __restrict__ Wq, const float* __restrict__ Wkv,
    const float* __restrict__ Wrel, const float* __restrict__ Wo,
    ushort* __restrict__ cb, ushort* __restrict__ pb,
    ushort* __restrict__ Wqt, ushort* __restrict__ Wkvt,
    ushort* __restrict__ Wrelt, ushort* __restrict__ Wot)
{
    __shared__ float t[32][33];
    int tid = threadIdx.x;
    if (blockIdx.x < 4096) {
        int idx = (blockIdx.x * 256 + tid) * 8;
        const float* s;
        ushort* d;
        if (idx < 2097152)      { s = memory + idx;              d = cb + idx; }
        else if (idx < 4194304) { s = x + (idx - 2097152);       d = cb + idx; }
        else                    { s = pos_emb + (idx - 4194304); d = pb + (idx - 4194304); }
        float4 a = *(const float4*)(s);
        float4 b = *(const float4*)(s + 4);
        u16x8v o;
        o[0] = f2bf(a.x); o[1] = f2bf(a.y); o[2] = f2bf(a.z); o[3] = f2bf(a.w);
        o[4] = f2bf(b.x); o[5] = f2bf(b.y); o[6] = f2bf(b.z); o[7] = f2bf(b.w);
        *(u16x8v*)d = o;
        return;
    }
    int tb = blockIdx.x - 4096;
    const float* src; ushort* dst; int N;
    if (tb < 1024)      { src = Wq;   dst = Wqt;   N = 1024; }
    else if (tb < 3072) { src = Wkv;  dst = Wkvt;  N = 2048; tb -= 1024; }
    else if (tb < 4096) { src = Wrel; dst = Wrelt; N = 1024; tb -= 3072; }
    else                { src = Wo;   dst = Wot;   N = 1024; tb -= 4096; }
    int k0 = (tb & 31) * 32, n0 = (tb >> 5) * 32;
    int r = tid >> 3, c4 = (tid & 7) * 4;
    float4 v = *(const float4*)(src + (size_t)(k0 + r) * N + n0 + c4);
    t[r][c4 + 0] = v.x; t[r][c4 + 1] = v.y; t[r][c4 + 2] = v.z; t[r][c4 + 3] = v.w;
    __syncthreads();
    u16x4v o;
    o[0] = f2bf(t[c4 + 0][r]); o[1] = f2bf(t[c4 + 1][r]);
    o[2] = f2bf(t[c4 + 2][r]); o[3] = f2bf(t[c4 + 3][r]);
    *(u16x4v*)(dst + (size_t)(n0 + r) * 1024 + k0 + c4) = o;
}

// ---------------------------------------------------------------------------
// Single-launch projections: 64x64-tile bf16 MFMA GEMM, flat grid 3584.
// blocks [0,512):    q   (M=2048 over x, N=1024, Wqt)  -> qu/qv [bh][L][64]
// blocks [512,2560): kv  (M=4096 over cat, N=2048, Wkvt) -> k [bh][T][64],
//                                                           v^T [bh][64][T]
// blocks [2560,3584): r  (M=4096 over pos, N=1024, Wrelt) -> [bh][T][64]
// ---------------------------------------------------------------------------
__global__ __launch_bounds__(256) void proj_all(
    const ushort* __restrict__ cb, const ushort* __restrict__ pb,
    const ushort* __restrict__ Wqt, const ushort* __restrict__ Wkvt,
    const ushort* __restrict__ Wrelt,
    const float* __restrict__ bu, const float* __restrict__ bv,
    ushort* __restrict__ quB, ushort* __restrict__ qvB,
    ushort* __restrict__ kbB, ushort* __restrict__ VtB,
    ushort* __restrict__ rbB)
{
    __shared__ ushort Al[64][40];
    __shared__ ushort Bl[64][40];
    int lin = blockIdx.x;
    int omode, M0, N0;
    const ushort *A, *Wt;
    if (lin < 512) {
        omode = 0; A = cb + 2097152; Wt = Wqt;
        M0 = (lin & 31) * 64; N0 = (lin >> 5) * 64;
    } else if (lin < 2560) {
        omode = 1; A = cb; Wt = Wkvt;
        int l2 = lin - 512;
        M0 = (l2 & 63) * 64; N0 = (l2 >> 6) * 64;
    } else {
        omode = 2; A = pb; Wt = Wrelt;
        int l2 = lin - 2560;
        M0 = (l2 & 63) * 64; N0 = (l2 >> 6) * 64;
    }
    int tid = threadIdx.x;
    int wid = tid >> 6, lane = tid & 63, quad = lane >> 4, jl = lane & 15;
    int m0w = (wid >> 1) * 32, n0w = (wid & 1) * 32;
    int sr = tid >> 2, sc = (tid & 3) * 8;

    f32x4 acc[2][2];
    #pragma unroll
    for (int i = 0; i < 2; ++i)
        #pragma unroll
        for (int j = 0; j < 2; ++j) acc[i][j] = (f32x4){0.f, 0.f, 0.f, 0.f};

    for (int k0 = 0; k0 < 1024; k0 += 32) {
        *(u16x8v*)&Al[sr][sc] = *(const u16x8v*)(A  + (size_t)(M0 + sr) * 1024 + k0 + sc);
        *(u16x8v*)&Bl[sr][sc] = *(const u16x8v*)(Wt + (size_t)(N0 + sr) * 1024 + k0 + sc);
        __syncthreads();
        bf16x8 a0 = *(const bf16x8*)&Al[m0w + jl][quad * 8];
        bf16x8 a1 = *(const bf16x8*)&Al[m0w + 16 + jl][quad * 8];
        bf16x8 b0 = *(const bf16x8*)&Bl[n0w + jl][quad * 8];
        bf16x8 b1 = *(const bf16x8*)&Bl[n0w + 16 + jl][quad * 8];
        acc[0][0] = MFMA16(a0, b0, acc[0][0]);
        acc[0][1] = MFMA16(a0, b1, acc[0][1]);
        acc[1][0] = MFMA16(a1, b0, acc[1][0]);
        acc[1][1] = MFMA16(a1, b1, acc[1][1]);
        __syncthreads();
    }

    #pragma unroll
    for (int ms = 0; ms < 2; ++ms)
        #pragma unroll
        for (int ns = 0; ns < 2; ++ns)
            #pragma unroll
            for (int r = 0; r < 4; ++r) {
                int gm = M0 + m0w + 16 * ms + quad * 4 + r;
                int gn = N0 + n0w + 16 * ns + jl;
                float v = acc[ms][ns][r];
                if (omode == 0) {
                    int l = gm >> 1, b = gm & 1;
                    int h = gn >> 6, d = gn & 63;
                    size_t o = ((size_t)((b << 4) | h) * 1024 + l) * 64 + d;
                    quB[o] = f2bf(v + bu[gn]);
                    qvB[o] = f2bf(v + bv[gn]);
                } else if (omode == 1) {
                    int t = gm >> 1, b = gm & 1;
                    int nn = gn & 1023;
                    int h = nn >> 6, d = nn & 63;
                    if (gn < 1024)
                        kbB[((size_t)((b << 4) | h) * 2048 + t) * 64 + d] = f2bf(v);
                    else
                        VtB[((size_t)((b << 4) | h) * 64 + d) * 2048 + t] = f2bf(v);
                } else {
                    int t = gm >> 1, b = gm & 1;
                    int h = gn >> 6, d = gn & 63;
                    rbB[((size_t)((b << 4) | h) * 2048 + t) * 64 + d] = f2bf(v);
                }
            }
}

// ---------------------------------------------------------------------------
// Output projection + residual: 64x64-tile, outF = OvecB @ Wot + resid (fp32)
// ---------------------------------------------------------------------------
__global__ __launch_bounds__(256) void gemm_o(
    const ushort* __restrict__ A, const ushort* __restrict__ Wt,
    const float* __restrict__ resid, float* __restrict__ outF)
{
    __shared__ ushort Al[64][40];
    __shared__ ushort Bl[64][40];
    int tid = threadIdx.x;
    int M0 = blockIdx.x * 64, N0 = blockIdx.y * 64;
    int wid = tid >> 6, lane = tid & 63, quad = lane >> 4, jl = lane & 15;
    int m0w = (wid >> 1) * 32, n0w = (wid & 1) * 32;
    int sr = tid >> 2, sc = (tid & 3) * 8;

    f32x4 acc[2][2];
    #pragma unroll
    for (int i = 0; i < 2; ++i)
        #pragma unroll
        for (int j = 0; j < 2; ++j) acc[i][j] = (f32x4){0.f, 0.f, 0.f, 0.f};

    for (int k0 = 0; k0 < 1024; k0 += 32) {
        *(u16x8v*)&Al[sr][sc] = *(const u16x8v*)(A  + (size_t)(M0 + sr) * 1024 + k0 + sc);
        *(u16x8v*)&Bl[sr][sc] = *(const u16x8v*)(Wt + (size_t)(N0 + sr) * 1024 + k0 + sc);
        __syncthreads();
        bf16x8 a0 = *(const bf16x8*)&Al[m0w + jl][quad * 8];
        bf16x8 a1 = *(const bf16x8*)&Al[m0w + 16 + jl][quad * 8];
        bf16x8 b0 = *(const bf16x8*)&Bl[n0w + jl][quad * 8];
        bf16x8 b1 = *(const bf16x8*)&Bl[n0w + 16 + jl][quad * 8];
        acc[0][0] = MFMA16(a0, b0, acc[0][0]);
        acc[0][1] = MFMA16(a0, b1, acc[0][1]);
        acc[1][0] = MFMA16(a1, b0, acc[1][0]);
        acc[1][1] = MFMA16(a1, b1, acc[1][1]);
        __syncthreads();
    }

    #pragma unroll
    for (int ms = 0; ms < 2; ++ms)
        #pragma unroll
        for (int ns = 0; ns < 2; ++ns)
            #pragma unroll
            for (int r = 0; r < 4; ++r) {
                int gm = M0 + m0w + 16 * ms + quad * 4 + r;
                int gn = N0 + n0w + 16 * ns + jl;
                outF[(size_t)gm * 1024 + gn] =
                    acc[ms][ns][r] + resid[(size_t)gm * 1024 + gn];
            }
}

// ---------------------------------------------------------------------------
// Score kernel: AC+BD -> p = exp(s*scale) -> packed NT store to [i][bh][j].
// ZERO LDS/fences. Quad repack via shfl: lane jl stores cols 4jl..4jl+3 (8 B),
// quad covers a full 128 B line -> no partial-line write amplification.
// ---------------------------------------------------------------------------
__global__ __launch_bounds__(256) void attn_score(
    const ushort* __restrict__ qu, const ushort* __restrict__ qv,
    const ushort* __restrict__ kb, const ushort* __restrict__ rb,
    float* __restrict__ lpart, ushort* __restrict__ AMw)
{
    int tid = threadIdx.x, wid = tid >> 6, lane = tid & 63;
    int quad = lane >> 4, jl = lane & 15;

    int lin  = blockIdx.x;
    int xcd  = lin & 7;
    int rest = lin >> 3;               // 0..255
    int bh   = (xcd << 2) | (rest & 3);
    int grp  = (rest >> 2) & 15;       // 64-row group
    int seg  = rest >> 6;              // 0..3
    int it   = grp * 4 + wid;
    int i0w  = it * 16;
    int nc   = 17 + grp;               // block-uniform
    int cb_  = seg * nc / 4;
    int ce_  = (seg + 1) * nc / 4;
    int irow = i0w + quad * 4;

    const ushort* kp  = kb + (size_t)bh * 2048 * 64;
    const ushort* rp  = rb + (size_t)bh * 2048 * 64;
    const ushort* qup = qu + (size_t)bh * 1024 * 64;
    const ushort* qvp = qv + (size_t)bh * 1024 * 64;

    bf16x8 quA[2], qvA[2];
    quA[0] = *(const bf16x8*)(qup + (size_t)(i0w + jl) * 64 + quad * 8);
    quA[1] = *(const bf16x8*)(qup + (size_t)(i0w + jl) * 64 + 32 + quad * 8);
    qvA[0] = *(const bf16x8*)(qvp + (size_t)(i0w + jl) * 64 + quad * 8);
    qvA[1] = *(const bf16x8*)(qvp + (size_t)(i0w + jl) * 64 + 32 + quad * 8);

    f32x4 z = (f32x4){0.f, 0.f, 0.f, 0.f};
    float lsum[4] = {0.f, 0.f, 0.f, 0.f};
    int bsrc = (quad << 4) | ((jl & 3) << 2);   // repack source lane base
    int sel  = jl >> 2;                          // repack source register

    for (int c = cb_; c < ce_; ++c) {
        int j0 = c * 64;
        // ---- AC: 4 column-subtiles of 16 ----
        f32x4 ac[4];
        #pragma unroll
        for (int su = 0; su < 4; ++su) {
            const ushort* krow = kp + (size_t)(j0 + su * 16 + jl) * 64;
            bf16x8 k0 = *(const bf16x8*)(krow + quad * 8);
            bf16x8 k1 = *(const bf16x8*)(krow + 32 + quad * 8);
            f32x4 t = MFMA16(quA[0], k0, z);
            ac[su] = MFMA16(quA[1], k1, t);
        }
        // ---- BD windows: 5 n-tiles covering r-rows d0 .. d0+79 ----
        int d0 = 1008 + j0 - i0w;
        f32x4 bt[5];
        #pragma unroll
        for (int nt = 0; nt < 5; ++nt) {
            int rr = d0 + nt * 16 + jl;
            rr = min(max(rr, 0), 2047);
            const ushort* rrow = rp + (size_t)rr * 64;
            bf16x8 r0 = *(const bf16x8*)(rrow + quad * 8);
            bf16x8 r1 = *(const bf16x8*)(rrow + 32 + quad * 8);
            f32x4 t = MFMA16(qvA[0], r0, z);
            bt[nt] = MFMA16(qvA[1], r1, t);
        }
        // ---- diagonal extraction, exp, repack, packed NT store ----
        #pragma unroll
        for (int r = 0; r < 4; ++r) {
            int ii = quad * 4 + r;
            int src = (quad << 4) | ((jl + 15 - ii) & 15);
            float bs[5];
            #pragma unroll
            for (int nt = 0; nt < 5; ++nt) bs[nt] = __shfl(bt[nt][r], src);
            bool hi = (jl > ii);
            float pv_[4];
            #pragma unroll
            for (int su = 0; su < 4; ++su) {
                float bd = hi ? bs[su + 1] : bs[su];
                float sv = (ac[su][r] + bd) * SCALE_;
                int j = j0 + su * 16 + jl;
                float p = (j <= irow + r + M_) ? __expf(fminf(sv, 60.f)) : 0.f;
                lsum[r] += p;
                pv_[su] = p;
            }
            // repack: lane jl takes cols 4jl..4jl+3 from register sel=jl>>2
            u16x4v st;
            #pragma unroll
            for (int e = 0; e < 4; ++e) {
                float v0 = __shfl(pv_[0], bsrc + e);
                float v1 = __shfl(pv_[1], bsrc + e);
                float v2 = __shfl(pv_[2], bsrc + e);
                float v3 = __shfl(pv_[3], bsrc + e);
                float vv = (sel == 0) ? v0 : (sel == 1) ? v1 : (sel == 2) ? v2 : v3;
                st[e] = f2bf(vv);
            }
            __builtin_nontemporal_store(st,
                (u16x4v*)(AMw + ((size_t)(irow + r) * 32 + bh) * 2048 + j0 + 4 * jl));
        }
    }

    // ---- epilogue: l partial sums ----
    #pragma unroll
    for (int r = 0; r < 4; ++r) {
        #pragma unroll
        for (int off = 1; off < 16; off <<= 1) lsum[r] += __shfl_xor(lsum[r], off);
        if (jl == 0) atomicAdd(&lpart[(size_t)bh * 1024 + irow + r], lsum[r]);
    }
}

// ---------------------------------------------------------------------------
// PV GEMM: O[bh][i][d] = (1/l_i) * sum_j P[i][bh][j] * V[bh][j][d].
// 64x64 tiles over (i,d); K bounded by the causal/written region 64*(17+mt).
// Epilogue folds o_combine: OvecB bf16 row-major + linvs for am_reduce.
// ---------------------------------------------------------------------------
__global__ __launch_bounds__(256) void pv_gemm(
    const ushort* __restrict__ P, const ushort* __restrict__ Vt,
    const float* __restrict__ lpart,
    ushort* __restrict__ OvecB, float* __restrict__ linvs)
{
    __shared__ ushort Al[64][40];
    __shared__ ushort Bl[64][40];
    int tid = threadIdx.x;
    int lin  = blockIdx.x;             // 512
    int xcd  = lin & 7;
    int rest = lin >> 3;               // 0..63
    int bh   = (xcd << 2) | (rest & 3);
    int mt   = rest >> 2;              // 0..15
    int M0   = mt * 64;
    int wid = tid >> 6, lane = tid & 63, quad = lane >> 4, jl = lane & 15;
    int m0w = (wid >> 1) * 32, n0w = (wid & 1) * 32;
    int sr = tid >> 2, sc = (tid & 3) * 8;

    const ushort* Bp = Vt + (size_t)bh * 64 * 2048;
    int kend = (17 + mt) * 64;

    f32x4 acc[2][2];
    #pragma unroll
    for (int i = 0; i < 2; ++i)
        #pragma unroll
        for (int j = 0; j < 2; ++j) acc[i][j] = (f32x4){0.f, 0.f, 0.f, 0.f};

    for (int k0 = 0; k0 < kend; k0 += 32) {
        *(u16x8v*)&Al[sr][sc] =
            *(const u16x8v*)(P + ((size_t)(M0 + sr) * 32 + bh) * 2048 + k0 + sc);
        *(u16x8v*)&Bl[sr][sc] = *(const u16x8v*)(Bp + (size_t)sr * 2048 + k0 + sc);
        __syncthreads();
        bf16x8 a0 = *(const bf16x8*)&Al[m0w + jl][quad * 8];
        bf16x8 a1 = *(const bf16x8*)&Al[m0w + 16 + jl][quad * 8];
        bf16x8 b0 = *(const bf16x8*)&Bl[n0w + jl][quad * 8];
        bf16x8 b1 = *(const bf16x8*)&Bl[n0w + 16 + jl][quad * 8];
        acc[0][0] = MFMA16(a0, b0, acc[0][0]);
        acc[0][1] = MFMA16(a0, b1, acc[0][1]);
        acc[1][0] = MFMA16(a1, b0, acc[1][0]);
        acc[1][1] = MFMA16(a1, b1, acc[1][1]);
        __syncthreads();
    }

    int b = bh >> 4, h = bh & 15;
    #pragma unroll
    for (int ms = 0; ms < 2; ++ms)
        #pragma unroll
        for (int r = 0; r < 4; ++r) {
            int gi = M0 + m0w + 16 * ms + quad * 4 + r;
            float linv = 1.f / lpart[(size_t)bh * 1024 + gi];
            #pragma unroll
            for (int ns = 0; ns < 2; ++ns) {
                int gd = n0w + 16 * ns + jl;
                OvecB[(size_t)(gi * 2 + b) * 1024 + h * 64 + gd] =
                    f2bf(acc[ms][ns][r] * linv);
            }
            if (n0w == 0 && jl == 0)
                linvs[(size_t)gi * 32 + bh] = linv * 0.03125f;
        }
}

// ---------------------------------------------------------------------------
// AM[i][j] = sum_bh plane[i][bh][j] * linvs[i][bh], re-masked.
// One block per row i: fully contiguous 128 KB stream per block.
// ---------------------------------------------------------------------------
__global__ __launch_bounds__(256) void am_reduce(const ushort* __restrict__ AMw,
                                                 const float* __restrict__ linvs,
                                                 float* __restrict__ AM) {
    __shared__ float lv[32];
    int i = blockIdx.x;
    int tid = threadIdx.x;
    if (tid < 32) lv[tid] = linvs[(size_t)i * 32 + tid];
    __syncthreads();
    int j0 = tid * 8;
    int jmax = i + M_;
    float acc[8];
    #pragma unroll
    for (int e = 0; e < 8; ++e) acc[e] = 0.f;
    if (j0 <= jmax) {
        const ushort* base = AMw + (size_t)i * 65536;
        for (int p = 0; p < 32; ++p) {
            float l = lv[p];
            u16x8v v = __builtin_nontemporal_load(
                (const u16x8v*)(base + (size_t)p * 2048 + j0));
            #pragma unroll
            for (int e = 0; e < 8; ++e) acc[e] += bf2f(v[e]) * l;
        }
    }
    float4 o0, o1;
    o0.x = (j0 + 0 <= jmax) ? acc[0] : 0.f;
    o0.y = (j0 + 1 <= jmax) ? acc[1] : 0.f;
    o0.z = (j0 + 2 <= jmax) ? acc[2] : 0.f;
    o0.w = (j0 + 3 <= jmax) ? acc[3] : 0.f;
    o1.x = (j0 + 4 <= jmax) ? acc[4] : 0.f;
    o1.y = (j0 + 5 <= jmax) ? acc[5] : 0.f;
    o1.z = (j0 + 6 <= jmax) ? acc[6] : 0.f;
    o1.w = (j0 + 7 <= jmax) ? acc[7] : 0.f;
    *(float4*)(AM + (size_t)i * 2048 + j0) = o0;
    *(float4*)(AM + (size_t)i * 2048 + j0 + 4) = o1;
}

// ---------------------------------------------------------------------------
// LayerNorm over D=1024, one block per row
// ---------------------------------------------------------------------------
__global__ __launch_bounds__(256) void ln_kernel(
    const float* __restrict__ hbuf,
    const float* __restrict__ gamma, const float* __restrict__ beta,
    float* __restrict__ out)
{
    __shared__ float rs[4], rss[4];
    int row = blockIdx.x;
    int tid = threadIdx.x;
    const float* hp = hbuf + (size_t)row * 1024;
    float4 h4 = *(const float4*)(hp + (tid << 2));
    float s = h4.x + h4.y + h4.z + h4.w;
    float ss = h4.x * h4.x + h4.y * h4.y + h4.z * h4.z + h4.w * h4.w;
    #pragma unroll
    for (int o = 32; o > 0; o >>= 1) {
        s  += __shfl_down(s, o);
        ss += __shfl_down(ss, o);
    }
    if ((tid & 63) == 0) { rs[tid >> 6] = s; rss[tid >> 6] = ss; }
    __syncthreads();
    float tot  = rs[0] + rs[1] + rs[2] + rs[3];
    float tots = rss[0] + rss[1] + rss[2] + rss[3];
    float mu = tot * (1.f / 1024.f);
    float var = tots * (1.f / 1024.f) - mu * mu;
    float rstd = rsqrtf(var + 1e-5f);
    float4 g4 = *(const float4*)(gamma + (tid << 2));
    float4 b4 = *(const float4*)(beta + (tid << 2));
    float4 o4;
    o4.x = (h4.x - mu) * rstd * g4.x + b4.x;
    o4.y = (h4.y - mu) * rstd * g4.y + b4.y;
    o4.z = (h4.z - mu) * rstd * g4.z + b4.z;
    o4.w = (h4.w - mu) * rstd * g4.w + b4.w;
    *(float4*)(out + (size_t)row * 1024 + (tid << 2)) = o4;
}

extern "C" void kernel_launch(void* const* d_in, const int* in_sizes, int n_in,
                              void* d_out, int out_size, void* d_ws, size_t ws_size,
                              hipStream_t stream) {
    const float* x       = (const float*)d_in[0];
    const float* pos_emb = (const float*)d_in[1];
    const float* memory  = (const float*)d_in[2];
    const float* bu      = (const float*)d_in[3];
    const float* bv      = (const float*)d_in[4];
    const float* Wq      = (const float*)d_in[6];
    const float* Wkv     = (const float*)d_in[7];
    const float* Wrel    = (const float*)d_in[8];
    const float* Wo      = (const float*)d_in[9];
    const float* gamma   = (const float*)d_in[10];
    const float* beta    = (const float*)d_in[11];

    float* out = (float*)d_out;
    float* AM  = out + (size_t)2097152;       // attn_matrix [L][T]

    ushort* cb    = (ushort*)d_ws;            // [4096][1024]
    ushort* pb    = cb    + 4194304;          // [4096][1024]
    ushort* Wqt   = pb    + 4194304;          // [1024][1024]
    ushort* Wkvt  = Wqt   + 1048576;          // [2048][1024]
    ushort* Wrelt = Wkvt  + 2097152;          // [1024][1024]
    ushort* Wot   = Wrelt + 1048576;          // [1024][1024]
    ushort* quB   = Wot   + 1048576;          // [32][1024][64]
    ushort* qvB   = quB   + 2097152;
    ushort* kbB   = qvB   + 2097152;          // [32][2048][64]
    ushort* VtB   = kbB   + 4194304;          // [32][64][2048]
    ushort* rbB   = VtB   + 4194304;          // [32][2048][64]
    ushort* OvecB = rbB   + 4194304;          // [2048][1024]
    float*  hbuf  = (float*)(OvecB + 2097152);// [2048][1024] fp32
    float*  lpart = hbuf  + 2097152;          // [32][1024] fp32
    float*  linvs = lpart + 32768;            // [1024][32] fp32
    ushort* AMw   = (ushort*)(linvs + 32768); // [1024][32][2048] bf16 (128 MB)

    dim3 blk(256);
    // fused converts + weight transposes
    prep<<<9216, blk, 0, stream>>>(memory, x, pos_emb, Wq, Wkv, Wrel, Wo,
                                   cb, pb, Wqt, Wkvt, Wrelt, Wot);
    hipMemsetAsync(lpart, 0, (size_t)32768 * sizeof(float), stream);

    // all projections in one launch
    proj_all<<<3584, blk, 0, stream>>>(cb, pb, Wqt, Wkvt, Wrelt, bu, bv,
                                       quB, qvB, kbB, VtB, rbB);
    // scores -> planes (fence-free, LDS-free, packed stores)
    attn_score<<<dim3(2048), blk, 0, stream>>>(quB, qvB, kbB, rbB, lpart, AMw);
    // PV as causal-K GEMM; folds o_combine
    pv_gemm<<<dim3(512), blk, 0, stream>>>(AMw, VtB, lpart, OvecB, linvs);
    // output projection + residual
    gemm_o<<<dim3(32, 16), blk, 0, stream>>>(OvecB, Wot, x, hbuf);
    // layernorm
    ln_kernel<<<2048, blk, 0, stream>>>(hbuf, gamma, beta, out);
    // attn_matrix reduction (streaming)
    am_reduce<<<1024, blk, 0, stream>>>(AMw, linvs, AM);
}

// Round 11
// 387.731 us; speedup vs baseline: 1.2193x; 1.0263x over previous
//
#include <hip/hip_runtime.h>
#include <math.h>
#include <stdint.h>

#define L_  1024
#define B_  2
#define D_  1024
#define H_  16
#define DH_ 64
#define M_  1024
#define T_  2048
#define SCALE_ 0.125f

typedef unsigned short ushort;
typedef short bf16x8 __attribute__((ext_vector_type(8)));
typedef float f32x4 __attribute__((ext_vector_type(4)));
typedef unsigned short u16x4v __attribute__((ext_vector_type(4)));
typedef unsigned short u16x8v __attribute__((ext_vector_type(8)));

#define MFMA16(a,b,c) __builtin_amdgcn_mfma_f32_16x16x32_bf16(a,b,c,0,0,0)

static __device__ __forceinline__ ushort f2bf(float x) {
    uint32_t u = __float_as_uint(x);
    uint32_t r = (u + 0x7FFFu + ((u >> 16) & 1u)) >> 16;
    return (ushort)r;
}
static __device__ __forceinline__ float bf2f(ushort h) {
    return __uint_as_float(((uint32_t)h) << 16);
}
// async global->LDS, 16B per lane; LDS dest = wave-uniform base + lane*16
static __device__ __forceinline__ void gl_lds16(const ushort* g, ushort* l) {
    __builtin_amdgcn_global_load_lds(
        (const __attribute__((address_space(1))) void*)g,
        (__attribute__((address_space(3))) void*)l, 16, 0, 0);
}

// ---------------------------------------------------------------------------
// Fused prep: fp32->bf16 converts (blocks 0..4095) + weight transposes
// (blocks 4096..9215; 32x32 tiles over Wq|Wkv|Wrel|Wo).
// ---------------------------------------------------------------------------
__global__ __launch_bounds__(256) void prep(
    const float* __restrict__ memory, const float* __restrict__ x,
    const float* __restrict__ pos_emb,
    const float* __restrict__ Wq, const float* __restrict__ Wkv,
    const float* __restrict__ Wrel, const float* __restrict__ Wo,
    ushort* __restrict__ cb, ushort* __restrict__ pb,
    ushort* __restrict__ Wqt, ushort* __restrict__ Wkvt,
    ushort* __restrict__ Wrelt, ushort* __restrict__ Wot)
{
    __shared__ float t[32][33];
    int tid = threadIdx.x;
    if (blockIdx.x < 4096) {
        int idx = (blockIdx.x * 256 + tid) * 8;
        const float* s;
        ushort* d;
        if (idx < 2097152)      { s = memory + idx;              d = cb + idx; }
        else if (idx < 4194304) { s = x + (idx - 2097152);       d = cb + idx; }
        else                    { s = pos_emb + (idx - 4194304); d = pb + (idx - 4194304); }
        float4 a = *(const float4*)(s);
        float4 b = *(const float4*)(s + 4);
        u16x8v o;
        o[0] = f2bf(a.x); o[1] = f2bf(a.y); o[2] = f2bf(a.z); o[3] = f2bf(a.w);
        o[4] = f2bf(b.x); o[5] = f2bf(b.y); o[6] = f2bf(b.z); o[7] = f2bf(b.w);
        *(u16x8v*)d = o;
        return;
    }
    int tb = blockIdx.x - 4096;
    const float* src; ushort* dst; int N;
    if (tb < 1024)      { src = Wq;   dst = Wqt;   N = 1024; }
    else if (tb < 3072) { src = Wkv;  dst = Wkvt;  N = 2048; tb -= 1024; }
    else if (tb < 4096) { src = Wrel; dst = Wrelt; N = 1024; tb -= 3072; }
    else                { src = Wo;   dst = Wot;   N = 1024; tb -= 4096; }
    int k0 = (tb & 31) * 32, n0 = (tb >> 5) * 32;
    int r = tid >> 3, c4 = (tid & 7) * 4;
    float4 v = *(const float4*)(src + (size_t)(k0 + r) * N + n0 + c4);
    t[r][c4 + 0] = v.x; t[r][c4 + 1] = v.y; t[r][c4 + 2] = v.z; t[r][c4 + 3] = v.w;
    __syncthreads();
    u16x4v o;
    o[0] = f2bf(t[c4 + 0][r]); o[1] = f2bf(t[c4 + 1][r]);
    o[2] = f2bf(t[c4 + 2][r]); o[3] = f2bf(t[c4 + 3][r]);
    *(u16x4v*)(dst + (size_t)(n0 + r) * 1024 + k0 + c4) = o;
}

// ---------------------------------------------------------------------------
// Single-launch projections, 128x128 m97 tiles (gl_lds16 staging, BK=32,
// 4 waves 2x2, 4x4 MFMA each). Flat grid 896:
//  [0,128):   q  (M=2048, N=1024, Wqt)  -> qu=(+bu)/qv=(+bv) [bh][L][64]
//  [128,640): kv (M=4096, N=2048, Wkvt) -> k [bh][T][64], v^T [bh][64][T]
//  [640,896): r  (M=4096, N=1024, Wrelt)-> [bh][T][64]
// ---------------------------------------------------------------------------
__global__ __launch_bounds__(256) void proj_all(
    const ushort* __restrict__ cb, const ushort* __restrict__ pb,
    const ushort* __restrict__ Wqt, const ushort* __restrict__ Wkvt,
    const ushort* __restrict__ Wrelt,
    const float* __restrict__ bu, const float* __restrict__ bv,
    ushort* __restrict__ quB, ushort* __restrict__ qvB,
    ushort* __restrict__ kbB, ushort* __restrict__ VtB,
    ushort* __restrict__ rbB)
{
    __shared__ ushort Al[128 * 32];
    __shared__ ushort Bl[128 * 32];
    int lin = blockIdx.x;
    int omode, M0, N0;
    const ushort *A, *Wt;
    if (lin < 128) {
        omode = 0; A = cb + 2097152; Wt = Wqt;
        M0 = (lin & 15) * 128; N0 = (lin >> 4) * 128;
    } else if (lin < 640) {
        omode = 1; A = cb; Wt = Wkvt;
        int l2 = lin - 128;
        M0 = (l2 & 31) * 128; N0 = (l2 >> 5) * 128;
    } else {
        omode = 2; A = pb; Wt = Wrelt;
        int l2 = lin - 640;
        M0 = (l2 & 31) * 128; N0 = (l2 >> 5) * 128;
    }
    int tid = threadIdx.x;
    int wid = tid >> 6, lane = tid & 63, quad = lane >> 4, jl = lane & 15;
    int wr = wid >> 1, wc = wid & 1;
    int srow = lane >> 2;
    int scol = (lane & 3) * 8;

    f32x4 acc[4][4];
    #pragma unroll
    for (int i = 0; i < 4; ++i)
        #pragma unroll
        for (int j = 0; j < 4; ++j) acc[i][j] = (f32x4){0.f, 0.f, 0.f, 0.f};

    for (int k0 = 0; k0 < 1024; k0 += 32) {
        #pragma unroll
        for (int c = 0; c < 2; ++c) {
            int r = wid * 32 + c * 16 + srow;
            gl_lds16(A  + (size_t)(M0 + r) * 1024 + k0 + scol,
                     Al + wid * 1024 + c * 512);
            gl_lds16(Wt + (size_t)(N0 + r) * 1024 + k0 + scol,
                     Bl + wid * 1024 + c * 512);
        }
        __syncthreads();
        bf16x8 af[4], bfr[4];
        #pragma unroll
        for (int mt = 0; mt < 4; ++mt)
            af[mt] = *(const bf16x8*)&Al[(wr * 64 + mt * 16 + jl) * 32 + quad * 8];
        #pragma unroll
        for (int nt = 0; nt < 4; ++nt)
            bfr[nt] = *(const bf16x8*)&Bl[(wc * 64 + nt * 16 + jl) * 32 + quad * 8];
        #pragma unroll
        for (int mt = 0; mt < 4; ++mt)
            #pragma unroll
            for (int nt = 0; nt < 4; ++nt)
                acc[mt][nt] = MFMA16(af[mt], bfr[nt], acc[mt][nt]);
        __syncthreads();
    }

    #pragma unroll
    for (int mt = 0; mt < 4; ++mt)
        #pragma unroll
        for (int nt = 0; nt < 4; ++nt)
            #pragma unroll
            for (int r = 0; r < 4; ++r) {
                int gm = M0 + wr * 64 + mt * 16 + quad * 4 + r;
                int gn = N0 + wc * 64 + nt * 16 + jl;
                float v = acc[mt][nt][r];
                if (omode == 0) {
                    int l = gm >> 1, b = gm & 1;
                    int h = gn >> 6, d = gn & 63;
                    size_t o = ((size_t)((b << 4) | h) * 1024 + l) * 64 + d;
                    quB[o] = f2bf(v + bu[gn]);
                    qvB[o] = f2bf(v + bv[gn]);
                } else if (omode == 1) {
                    int t = gm >> 1, b = gm & 1;
                    int nn = gn & 1023;
                    int h = nn >> 6, d = nn & 63;
                    if (gn < 1024)
                        kbB[((size_t)((b << 4) | h) * 2048 + t) * 64 + d] = f2bf(v);
                    else
                        VtB[((size_t)((b << 4) | h) * 64 + d) * 2048 + t] = f2bf(v);
                } else {
                    int t = gm >> 1, b = gm & 1;
                    int h = gn >> 6, d = gn & 63;
                    rbB[((size_t)((b << 4) | h) * 2048 + t) * 64 + d] = f2bf(v);
                }
            }
}

// ---------------------------------------------------------------------------
// Output projection + residual: 64x64-tile, outF = OvecB @ Wot + resid (fp32)
// ---------------------------------------------------------------------------
__global__ __launch_bounds__(256) void gemm_o(
    const ushort* __restrict__ A, const ushort* __restrict__ Wt,
    const float* __restrict__ resid, float* __restrict__ outF)
{
    __shared__ ushort Al[64][40];
    __shared__ ushort Bl[64][40];
    int tid = threadIdx.x;
    int M0 = blockIdx.x * 64, N0 = blockIdx.y * 64;
    int wid = tid >> 6, lane = tid & 63, quad = lane >> 4, jl = lane & 15;
    int m0w = (wid >> 1) * 32, n0w = (wid & 1) * 32;
    int sr = tid >> 2, sc = (tid & 3) * 8;

    f32x4 acc[2][2];
    #pragma unroll
    for (int i = 0; i < 2; ++i)
        #pragma unroll
        for (int j = 0; j < 2; ++j) acc[i][j] = (f32x4){0.f, 0.f, 0.f, 0.f};

    for (int k0 = 0; k0 < 1024; k0 += 32) {
        *(u16x8v*)&Al[sr][sc] = *(const u16x8v*)(A  + (size_t)(M0 + sr) * 1024 + k0 + sc);
        *(u16x8v*)&Bl[sr][sc] = *(const u16x8v*)(Wt + (size_t)(N0 + sr) * 1024 + k0 + sc);
        __syncthreads();
        bf16x8 a0 = *(const bf16x8*)&Al[m0w + jl][quad * 8];
        bf16x8 a1 = *(const bf16x8*)&Al[m0w + 16 + jl][quad * 8];
        bf16x8 b0 = *(const bf16x8*)&Bl[n0w + jl][quad * 8];
        bf16x8 b1 = *(const bf16x8*)&Bl[n0w + 16 + jl][quad * 8];
        acc[0][0] = MFMA16(a0, b0, acc[0][0]);
        acc[0][1] = MFMA16(a0, b1, acc[0][1]);
        acc[1][0] = MFMA16(a1, b0, acc[1][0]);
        acc[1][1] = MFMA16(a1, b1, acc[1][1]);
        __syncthreads();
    }

    #pragma unroll
    for (int ms = 0; ms < 2; ++ms)
        #pragma unroll
        for (int ns = 0; ns < 2; ++ns)
            #pragma unroll
            for (int r = 0; r < 4; ++r) {
                int gm = M0 + m0w + 16 * ms + quad * 4 + r;
                int gn = N0 + n0w + 16 * ns + jl;
                outF[(size_t)gm * 1024 + gn] =
                    acc[ms][ns][r] + resid[(size_t)gm * 1024 + gn];
            }
}

// ---------------------------------------------------------------------------
// Score kernel: AC+BD -> p = exp(s*scale) -> scalar NT stores to [i][bh][j].
// ZERO LDS / fences / barriers (R9-measured fastest variant).
// Block = 4 waves, same bh+seg, adjacent i-tiles (L1 sharing); XCD-bh binding.
// ---------------------------------------------------------------------------
__global__ __launch_bounds__(256) void attn_score(
    const ushort* __restrict__ qu, const ushort* __restrict__ qv,
    const ushort* __restrict__ kb, const ushort* __restrict__ rb,
    float* __restrict__ lpart, ushort* __restrict__ AMw)
{
    int tid = threadIdx.x, wid = tid >> 6, lane = tid & 63;
    int quad = lane >> 4, jl = lane & 15;

    int lin  = blockIdx.x;
    int xcd  = lin & 7;
    int rest = lin >> 3;               // 0..255
    int bh   = (xcd << 2) | (rest & 3);
    int grp  = (rest >> 2) & 15;       // 64-row group
    int seg  = rest >> 6;              // 0..3
    int it   = grp * 4 + wid;
    int i0w  = it * 16;
    int nc   = 17 + grp;               // block-uniform
    int cb_  = seg * nc / 4;
    int ce_  = (seg + 1) * nc / 4;
    int irow = i0w + quad * 4;

    const ushort* kp  = kb + (size_t)bh * 2048 * 64;
    const ushort* rp  = rb + (size_t)bh * 2048 * 64;
    const ushort* qup = qu + (size_t)bh * 1024 * 64;
    const ushort* qvp = qv + (size_t)bh * 1024 * 64;

    bf16x8 quA[2], qvA[2];
    quA[0] = *(const bf16x8*)(qup + (size_t)(i0w + jl) * 64 + quad * 8);
    quA[1] = *(const bf16x8*)(qup + (size_t)(i0w + jl) * 64 + 32 + quad * 8);
    qvA[0] = *(const bf16x8*)(qvp + (size_t)(i0w + jl) * 64 + quad * 8);
    qvA[1] = *(const bf16x8*)(qvp + (size_t)(i0w + jl) * 64 + 32 + quad * 8);

    f32x4 z = (f32x4){0.f, 0.f, 0.f, 0.f};
    float lsum[4] = {0.f, 0.f, 0.f, 0.f};

    for (int c = cb_; c < ce_; ++c) {
        int j0 = c * 64;
        // ---- AC: 4 column-subtiles of 16 ----
        f32x4 ac[4];
        #pragma unroll
        for (int su = 0; su < 4; ++su) {
            const ushort* krow = kp + (size_t)(j0 + su * 16 + jl) * 64;
            bf16x8 k0 = *(const bf16x8*)(krow + quad * 8);
            bf16x8 k1 = *(const bf16x8*)(krow + 32 + quad * 8);
            f32x4 t = MFMA16(quA[0], k0, z);
            ac[su] = MFMA16(quA[1], k1, t);
        }
        // ---- BD windows: 5 n-tiles covering r-rows d0 .. d0+79 ----
        int d0 = 1008 + j0 - i0w;
        f32x4 bt[5];
        #pragma unroll
        for (int nt = 0; nt < 5; ++nt) {
            int rr = d0 + nt * 16 + jl;
            rr = min(max(rr, 0), 2047);
            const ushort* rrow = rp + (size_t)rr * 64;
            bf16x8 r0 = *(const bf16x8*)(rrow + quad * 8);
            bf16x8 r1 = *(const bf16x8*)(rrow + 32 + quad * 8);
            f32x4 t = MFMA16(qvA[0], r0, z);
            bt[nt] = MFMA16(qvA[1], r1, t);
        }
        // ---- diagonal extraction, exp, scalar NT store in C-layout ----
        #pragma unroll
        for (int r = 0; r < 4; ++r) {
            int ii = quad * 4 + r;
            int src = (quad << 4) | ((jl + 15 - ii) & 15);
            float bs[5];
            #pragma unroll
            for (int nt = 0; nt < 5; ++nt) bs[nt] = __shfl(bt[nt][r], src);
            bool hi = (jl > ii);
            ushort* prow = AMw + ((size_t)(irow + r) * 32 + bh) * 2048 + j0 + jl;
            #pragma unroll
            for (int su = 0; su < 4; ++su) {
                float bd = hi ? bs[su + 1] : bs[su];
                float sv = (ac[su][r] + bd) * SCALE_;
                int j = j0 + su * 16 + jl;
                float p = (j <= irow + r + M_) ? __expf(fminf(sv, 60.f)) : 0.f;
                lsum[r] += p;
                __builtin_nontemporal_store(f2bf(p), prow + su * 16);
            }
        }
    }

    // ---- epilogue: l partial sums ----
    #pragma unroll
    for (int r = 0; r < 4; ++r) {
        #pragma unroll
        for (int off = 1; off < 16; off <<= 1) lsum[r] += __shfl_xor(lsum[r], off);
        if (jl == 0) atomicAdd(&lpart[(size_t)bh * 1024 + irow + r], lsum[r]);
    }
}

// ---------------------------------------------------------------------------
// PV GEMM: O[bh][i][d] = (1/l_i) * sum_j P[i][bh][j] * V[bh][j][d].
// 64x64 tiles over (i,d); K bounded by the causal/written region 64*(17+mt).
// Epilogue folds o_combine: OvecB bf16 row-major + linvs for am_reduce.
// ---------------------------------------------------------------------------
__global__ __launch_bounds__(256) void pv_gemm(
    const ushort* __restrict__ P, const ushort* __restrict__ Vt,
    const float* __restrict__ lpart,
    ushort* __restrict__ OvecB, float* __restrict__ linvs)
{
    __shared__ ushort Al[64][40];
    __shared__ ushort Bl[64][40];
    int tid = threadIdx.x;
    int lin  = blockIdx.x;             // 512
    int xcd  = lin & 7;
    int rest = lin >> 3;               // 0..63
    int bh   = (xcd << 2) | (rest & 3);
    int mt   = rest >> 2;              // 0..15
    int M0   = mt * 64;
    int wid = tid >> 6, lane = tid & 63, quad = lane >> 4, jl = lane & 15;
    int m0w = (wid >> 1) * 32, n0w = (wid & 1) * 32;
    int sr = tid >> 2, sc = (tid & 3) * 8;

    const ushort* Bp = Vt + (size_t)bh * 64 * 2048;
    int kend = (17 + mt) * 64;

    f32x4 acc[2][2];
    #pragma unroll
    for (int i = 0; i < 2; ++i)
        #pragma unroll
        for (int j = 0; j < 2; ++j) acc[i][j] = (f32x4){0.f, 0.f, 0.f, 0.f};

    for (int k0 = 0; k0 < kend; k0 += 32) {
        *(u16x8v*)&Al[sr][sc] =
            *(const u16x8v*)(P + ((size_t)(M0 + sr) * 32 + bh) * 2048 + k0 + sc);
        *(u16x8v*)&Bl[sr][sc] = *(const u16x8v*)(Bp + (size_t)sr * 2048 + k0 + sc);
        __syncthreads();
        bf16x8 a0 = *(const bf16x8*)&Al[m0w + jl][quad * 8];
        bf16x8 a1 = *(const bf16x8*)&Al[m0w + 16 + jl][quad * 8];
        bf16x8 b0 = *(const bf16x8*)&Bl[n0w + jl][quad * 8];
        bf16x8 b1 = *(const bf16x8*)&Bl[n0w + 16 + jl][quad * 8];
        acc[0][0] = MFMA16(a0, b0, acc[0][0]);
        acc[0][1] = MFMA16(a0, b1, acc[0][1]);
        acc[1][0] = MFMA16(a1, b0, acc[1][0]);
        acc[1][1] = MFMA16(a1, b1, acc[1][1]);
        __syncthreads();
    }

    int b = bh >> 4, h = bh & 15;
    #pragma unroll
    for (int ms = 0; ms < 2; ++ms)
        #pragma unroll
        for (int r = 0; r < 4; ++r) {
            int gi = M0 + m0w + 16 * ms + quad * 4 + r;
            float linv = 1.f / lpart[(size_t)bh * 1024 + gi];
            #pragma unroll
            for (int ns = 0; ns < 2; ++ns) {
                int gd = n0w + 16 * ns + jl;
                OvecB[(size_t)(gi * 2 + b) * 1024 + h * 64 + gd] =
                    f2bf(acc[ms][ns][r] * linv);
            }
            if (n0w == 0 && jl == 0)
                linvs[(size_t)gi * 32 + bh] = linv * 0.03125f;
        }
}

// ---------------------------------------------------------------------------
// AM[i][j] = sum_bh plane[i][bh][j] * linvs[i][bh], re-masked.
// One block per row i: fully contiguous 128 KB stream per block.
// ---------------------------------------------------------------------------
__global__ __launch_bounds__(256) void am_reduce(const ushort* __restrict__ AMw,
                                                 const float* __restrict__ linvs,
                                                 float* __restrict__ AM) {
    __shared__ float lv[32];
    int i = blockIdx.x;
    int tid = threadIdx.x;
    if (tid < 32) lv[tid] = linvs[(size_t)i * 32 + tid];
    __syncthreads();
    int j0 = tid * 8;
    int jmax = i + M_;
    float acc[8];
    #pragma unroll
    for (int e = 0; e < 8; ++e) acc[e] = 0.f;
    if (j0 <= jmax) {
        const ushort* base = AMw + (size_t)i * 65536;
        for (int p = 0; p < 32; ++p) {
            float l = lv[p];
            u16x8v v = __builtin_nontemporal_load(
                (const u16x8v*)(base + (size_t)p * 2048 + j0));
            #pragma unroll
            for (int e = 0; e < 8; ++e) acc[e] += bf2f(v[e]) * l;
        }
    }
    float4 o0, o1;
    o0.x = (j0 + 0 <= jmax) ? acc[0] : 0.f;
    o0.y = (j0 + 1 <= jmax) ? acc[1] : 0.f;
    o0.z = (j0 + 2 <= jmax) ? acc[2] : 0.f;
    o0.w = (j0 + 3 <= jmax) ? acc[3] : 0.f;
    o1.x = (j0 + 4 <= jmax) ? acc[4] : 0.f;
    o1.y = (j0 + 5 <= jmax) ? acc[5] : 0.f;
    o1.z = (j0 + 6 <= jmax) ? acc[6] : 0.f;
    o1.w = (j0 + 7 <= jmax) ? acc[7] : 0.f;
    *(float4*)(AM + (size_t)i * 2048 + j0) = o0;
    *(float4*)(AM + (size_t)i * 2048 + j0 + 4) = o1;
}

// ---------------------------------------------------------------------------
// LayerNorm over D=1024, one block per row
// ---------------------------------------------------------------------------
__global__ __launch_bounds__(256) void ln_kernel(
    const float* __restrict__ hbuf,
    const float* __restrict__ gamma, const float* __restrict__ beta,
    float* __restrict__ out)
{
    __shared__ float rs[4], rss[4];
    int row = blockIdx.x;
    int tid = threadIdx.x;
    const float* hp = hbuf + (size_t)row * 1024;
    float4 h4 = *(const float4*)(hp + (tid << 2));
    float s = h4.x + h4.y + h4.z + h4.w;
    float ss = h4.x * h4.x + h4.y * h4.y + h4.z * h4.z + h4.w * h4.w;
    #pragma unroll
    for (int o = 32; o > 0; o >>= 1) {
        s  += __shfl_down(s, o);
        ss += __shfl_down(ss, o);
    }
    if ((tid & 63) == 0) { rs[tid >> 6] = s; rss[tid >> 6] = ss; }
    __syncthreads();
    float tot  = rs[0] + rs[1] + rs[2] + rs[3];
    float tots = rss[0] + rss[1] + rss[2] + rss[3];
    float mu = tot * (1.f / 1024.f);
    float var = tots * (1.f / 1024.f) - mu * mu;
    float rstd = rsqrtf(var + 1e-5f);
    float4 g4 = *(const float4*)(gamma + (tid << 2));
    float4 b4 = *(const float4*)(beta + (tid << 2));
    float4 o4;
    o4.x = (h4.x - mu) * rstd * g4.x + b4.x;
    o4.y = (h4.y - mu) * rstd * g4.y + b4.y;
    o4.z = (h4.z - mu) * rstd * g4.z + b4.z;
    o4.w = (h4.w - mu) * rstd * g4.w + b4.w;
    *(float4*)(out + (size_t)row * 1024 + (tid << 2)) = o4;
}

extern "C" void kernel_launch(void* const* d_in, const int* in_sizes, int n_in,
                              void* d_out, int out_size, void* d_ws, size_t ws_size,
                              hipStream_t stream) {
    const float* x       = (const float*)d_in[0];
    const float* pos_emb = (const float*)d_in[1];
    const float* memory  = (const float*)d_in[2];
    const float* bu      = (const float*)d_in[3];
    const float* bv      = (const float*)d_in[4];
    const float* Wq      = (const float*)d_in[6];
    const float* Wkv     = (const float*)d_in[7];
    const float* Wrel    = (const float*)d_in[8];
    const float* Wo      = (const float*)d_in[9];
    const float* gamma   = (const float*)d_in[10];
    const float* beta    = (const float*)d_in[11];

    float* out = (float*)d_out;
    float* AM  = out + (size_t)2097152;       // attn_matrix [L][T]

    ushort* cb    = (ushort*)d_ws;            // [4096][1024]
    ushort* pb    = cb    + 4194304;          // [4096][1024]
    ushort* Wqt   = pb    + 4194304;          // [1024][1024]
    ushort* Wkvt  = Wqt   + 1048576;          // [2048][1024]
    ushort* Wrelt = Wkvt  + 2097152;          // [1024][1024]
    ushort* Wot   = Wrelt + 1048576;          // [1024][1024]
    ushort* quB   = Wot   + 1048576;          // [32][1024][64]
    ushort* qvB   = quB   + 2097152;
    ushort* kbB   = qvB   + 2097152;          // [32][2048][64]
    ushort* VtB   = kbB   + 4194304;          // [32][64][2048]
    ushort* rbB   = VtB   + 4194304;          // [32][2048][64]
    ushort* OvecB = rbB   + 4194304;          // [2048][1024]
    float*  hbuf  = (float*)(OvecB + 2097152);// [2048][1024] fp32
    float*  lpart = hbuf  + 2097152;          // [32][1024] fp32
    float*  linvs = lpart + 32768;            // [1024][32] fp32
    ushort* AMw   = (ushort*)(linvs + 32768); // [1024][32][2048] bf16 (128 MB)

    dim3 blk(256);
    // fused converts + weight transposes
    prep<<<9216, blk, 0, stream>>>(memory, x, pos_emb, Wq, Wkv, Wrel, Wo,
                                   cb, pb, Wqt, Wkvt, Wrelt, Wot);
    hipMemsetAsync(lpart, 0, (size_t)32768 * sizeof(float), stream);

    // all projections in one 128x128-tile launch (896 blocks)
    proj_all<<<896, blk, 0, stream>>>(cb, pb, Wqt, Wkvt, Wrelt, bu, bv,
                                      quB, qvB, kbB, VtB, rbB);
    // scores -> planes (fence-free, LDS-free, scalar NT stores)
    attn_score<<<dim3(2048), blk, 0, stream>>>(quB, qvB, kbB, rbB, lpart, AMw);
    // PV as causal-K GEMM; folds o_combine
    pv_gemm<<<dim3(512), blk, 0, stream>>>(AMw, VtB, lpart, OvecB, linvs);
    // output projection + residual
    gemm_o<<<dim3(32, 16), blk, 0, stream>>>(OvecB, Wot, x, hbuf);
    // layernorm
    ln_kernel<<<2048, blk, 0, stream>>>(hbuf, gamma, beta, out);
    // attn_matrix reduction (streaming)
    am_reduce<<<1024, blk, 0, stream>>>(AMw, linvs, AM);
}

// Round 12
// 377.063 us; speedup vs baseline: 1.2538x; 1.0283x over previous
//
#include <hip/hip_runtime.h>
#include <math.h>
#include <stdint.h>

#define L_  1024
#define B_  2
#define D_  1024
#define H_  16
#define DH_ 64
#define M_  1024
#define T_  2048
#define SCALE_ 0.125f
#define SCALE2_ 0.18033688f   // 0.125 * log2(e)

typedef unsigned short ushort;
typedef short bf16x8 __attribute__((ext_vector_type(8)));
typedef float f32x4 __attribute__((ext_vector_type(4)));
typedef unsigned short u16x4v __attribute__((ext_vector_type(4)));
typedef unsigned short u16x8v __attribute__((ext_vector_type(8)));

#define MFMA16(a,b,c) __builtin_amdgcn_mfma_f32_16x16x32_bf16(a,b,c,0,0,0)

static __device__ __forceinline__ ushort f2bf(float x) {
    uint32_t u = __float_as_uint(x);
    uint32_t r = (u + 0x7FFFu + ((u >> 16) & 1u)) >> 16;
    return (ushort)r;
}
// fast round-half-up (hot path only; <=0.5 ULP bias, fine vs 0.0988 threshold)
static __device__ __forceinline__ ushort f2bf_fast(float x) {
    return (ushort)((__float_as_uint(x) + 0x8000u) >> 16);
}
static __device__ __forceinline__ float bf2f(ushort h) {
    return __uint_as_float(((uint32_t)h) << 16);
}
// async global->LDS, 16B per lane; LDS dest = wave-uniform base + lane*16
static __device__ __forceinline__ void gl_lds16(const ushort* g, ushort* l) {
    __builtin_amdgcn_global_load_lds(
        (const __attribute__((address_space(1))) void*)g,
        (__attribute__((address_space(3))) void*)l, 16, 0, 0);
}

// ---------------------------------------------------------------------------
// Fused prep: fp32->bf16 converts (blocks 0..4095), weight transposes
// (4096..9215), lpart zero-fill (9216..9247).
// ---------------------------------------------------------------------------
__global__ __launch_bounds__(256) void prep(
    const float* __restrict__ memory, const float* __restrict__ x,
    const float* __restrict__ pos_emb,
    const float* __restrict__ Wq, const float* __restrict__ Wkv,
    const float* __restrict__ Wrel, const float* __restrict__ Wo,
    ushort* __restrict__ cb, ushort* __restrict__ pb,
    ushort* __restrict__ Wqt, ushort* __restrict__ Wkvt,
    ushort* __restrict__ Wrelt, ushort* __restrict__ Wot,
    float* __restrict__ lpart)
{
    __shared__ float t[32][33];
    int tid = threadIdx.x;
    if (blockIdx.x >= 9216) {
        int i = ((blockIdx.x - 9216) * 256 + tid) * 4;
        *(float4*)(lpart + i) = (float4){0.f, 0.f, 0.f, 0.f};
        return;
    }
    if (blockIdx.x < 4096) {
        int idx = (blockIdx.x * 256 + tid) * 8;
        const float* s;
        ushort* d;
        if (idx < 2097152)      { s = memory + idx;              d = cb + idx; }
        else if (idx < 4194304) { s = x + (idx - 2097152);       d = cb + idx; }
        else                    { s = pos_emb + (idx - 4194304); d = pb + (idx - 4194304); }
        float4 a = *(const float4*)(s);
        float4 b = *(const float4*)(s + 4);
        u16x8v o;
        o[0] = f2bf(a.x); o[1] = f2bf(a.y); o[2] = f2bf(a.z); o[3] = f2bf(a.w);
        o[4] = f2bf(b.x); o[5] = f2bf(b.y); o[6] = f2bf(b.z); o[7] = f2bf(b.w);
        *(u16x8v*)d = o;
        return;
    }
    int tb = blockIdx.x - 4096;
    const float* src; ushort* dst; int N;
    if (tb < 1024)      { src = Wq;   dst = Wqt;   N = 1024; }
    else if (tb < 3072) { src = Wkv;  dst = Wkvt;  N = 2048; tb -= 1024; }
    else if (tb < 4096) { src = Wrel; dst = Wrelt; N = 1024; tb -= 3072; }
    else                { src = Wo;   dst = Wot;   N = 1024; tb -= 4096; }
    int k0 = (tb & 31) * 32, n0 = (tb >> 5) * 32;
    int r = tid >> 3, c4 = (tid & 7) * 4;
    float4 v = *(const float4*)(src + (size_t)(k0 + r) * N + n0 + c4);
    t[r][c4 + 0] = v.x; t[r][c4 + 1] = v.y; t[r][c4 + 2] = v.z; t[r][c4 + 3] = v.w;
    __syncthreads();
    u16x4v o;
    o[0] = f2bf(t[c4 + 0][r]); o[1] = f2bf(t[c4 + 1][r]);
    o[2] = f2bf(t[c4 + 2][r]); o[3] = f2bf(t[c4 + 3][r]);
    *(u16x4v*)(dst + (size_t)(n0 + r) * 1024 + k0 + c4) = o;
}

// ---------------------------------------------------------------------------
// Single-launch projections, 128x128 m97 tiles (gl_lds16 staging, BK=32,
// 4 waves 2x2, 4x4 MFMA each). Flat grid 896.
// ---------------------------------------------------------------------------
__global__ __launch_bounds__(256) void proj_all(
    const ushort* __restrict__ cb, const ushort* __restrict__ pb,
    const ushort* __restrict__ Wqt, const ushort* __restrict__ Wkvt,
    const ushort* __restrict__ Wrelt,
    const float* __restrict__ bu, const float* __restrict__ bv,
    ushort* __restrict__ quB, ushort* __restrict__ qvB,
    ushort* __restrict__ kbB, ushort* __restrict__ VtB,
    ushort* __restrict__ rbB)
{
    __shared__ ushort Al[128 * 32];
    __shared__ ushort Bl[128 * 32];
    int lin = blockIdx.x;
    int omode, M0, N0;
    const ushort *A, *Wt;
    if (lin < 128) {
        omode = 0; A = cb + 2097152; Wt = Wqt;
        M0 = (lin & 15) * 128; N0 = (lin >> 4) * 128;
    } else if (lin < 640) {
        omode = 1; A = cb; Wt = Wkvt;
        int l2 = lin - 128;
        M0 = (l2 & 31) * 128; N0 = (l2 >> 5) * 128;
    } else {
        omode = 2; A = pb; Wt = Wrelt;
        int l2 = lin - 640;
        M0 = (l2 & 31) * 128; N0 = (l2 >> 5) * 128;
    }
    int tid = threadIdx.x;
    int wid = tid >> 6, lane = tid & 63, quad = lane >> 4, jl = lane & 15;
    int wr = wid >> 1, wc = wid & 1;
    int srow = lane >> 2;
    int scol = (lane & 3) * 8;

    f32x4 acc[4][4];
    #pragma unroll
    for (int i = 0; i < 4; ++i)
        #pragma unroll
        for (int j = 0; j < 4; ++j) acc[i][j] = (f32x4){0.f, 0.f, 0.f, 0.f};

    for (int k0 = 0; k0 < 1024; k0 += 32) {
        #pragma unroll
        for (int c = 0; c < 2; ++c) {
            int r = wid * 32 + c * 16 + srow;
            gl_lds16(A  + (size_t)(M0 + r) * 1024 + k0 + scol,
                     Al + wid * 1024 + c * 512);
            gl_lds16(Wt + (size_t)(N0 + r) * 1024 + k0 + scol,
                     Bl + wid * 1024 + c * 512);
        }
        __syncthreads();
        bf16x8 af[4], bfr[4];
        #pragma unroll
        for (int mt = 0; mt < 4; ++mt)
            af[mt] = *(const bf16x8*)&Al[(wr * 64 + mt * 16 + jl) * 32 + quad * 8];
        #pragma unroll
        for (int nt = 0; nt < 4; ++nt)
            bfr[nt] = *(const bf16x8*)&Bl[(wc * 64 + nt * 16 + jl) * 32 + quad * 8];
        #pragma unroll
        for (int mt = 0; mt < 4; ++mt)
            #pragma unroll
            for (int nt = 0; nt < 4; ++nt)
                acc[mt][nt] = MFMA16(af[mt], bfr[nt], acc[mt][nt]);
        __syncthreads();
    }

    #pragma unroll
    for (int mt = 0; mt < 4; ++mt)
        #pragma unroll
        for (int nt = 0; nt < 4; ++nt)
            #pragma unroll
            for (int r = 0; r < 4; ++r) {
                int gm = M0 + wr * 64 + mt * 16 + quad * 4 + r;
                int gn = N0 + wc * 64 + nt * 16 + jl;
                float v = acc[mt][nt][r];
                if (omode == 0) {
                    int l = gm >> 1, b = gm & 1;
                    int h = gn >> 6, d = gn & 63;
                    size_t o = ((size_t)((b << 4) | h) * 1024 + l) * 64 + d;
                    quB[o] = f2bf(v + bu[gn]);
                    qvB[o] = f2bf(v + bv[gn]);
                } else if (omode == 1) {
                    int t = gm >> 1, b = gm & 1;
                    int nn = gn & 1023;
                    int h = nn >> 6, d = nn & 63;
                    if (gn < 1024)
                        kbB[((size_t)((b << 4) | h) * 2048 + t) * 64 + d] = f2bf(v);
                    else
                        VtB[((size_t)((b << 4) | h) * 64 + d) * 2048 + t] = f2bf(v);
                } else {
                    int t = gm >> 1, b = gm & 1;
                    int h = gn >> 6, d = gn & 63;
                    rbB[((size_t)((b << 4) | h) * 2048 + t) * 64 + d] = f2bf(v);
                }
            }
}

// ---------------------------------------------------------------------------
// Score kernel: AC+BD -> p = exp2(s*SCALE2) -> scalar NT stores to [i][bh][j].
// ZERO LDS/fences. Interior chunks skip mask+clamp entirely (wave-uniform).
// ---------------------------------------------------------------------------
__global__ __launch_bounds__(256) void attn_score(
    const ushort* __restrict__ qu, const ushort* __restrict__ qv,
    const ushort* __restrict__ kb, const ushort* __restrict__ rb,
    float* __restrict__ lpart, ushort* __restrict__ AMw)
{
    int tid = threadIdx.x, wid = tid >> 6, lane = tid & 63;
    int quad = lane >> 4, jl = lane & 15;

    int lin  = blockIdx.x;
    int xcd  = lin & 7;
    int rest = lin >> 3;               // 0..255
    int bh   = (xcd << 2) | (rest & 3);
    int grp  = (rest >> 2) & 15;       // 64-row group
    int seg  = rest >> 6;              // 0..3
    int it   = grp * 4 + wid;
    int i0w  = it * 16;
    int nc   = 17 + grp;               // block-uniform
    int cb_  = seg * nc / 4;
    int ce_  = (seg + 1) * nc / 4;
    int irow = i0w + quad * 4;

    const ushort* kp  = kb + (size_t)bh * 2048 * 64;
    const ushort* rp  = rb + (size_t)bh * 2048 * 64;
    const ushort* qup = qu + (size_t)bh * 1024 * 64;
    const ushort* qvp = qv + (size_t)bh * 1024 * 64;

    bf16x8 quA[2], qvA[2];
    quA[0] = *(const bf16x8*)(qup + (size_t)(i0w + jl) * 64 + quad * 8);
    quA[1] = *(const bf16x8*)(qup + (size_t)(i0w + jl) * 64 + 32 + quad * 8);
    qvA[0] = *(const bf16x8*)(qvp + (size_t)(i0w + jl) * 64 + quad * 8);
    qvA[1] = *(const bf16x8*)(qvp + (size_t)(i0w + jl) * 64 + 32 + quad * 8);

    f32x4 z = (f32x4){0.f, 0.f, 0.f, 0.f};
    float lsum[4] = {0.f, 0.f, 0.f, 0.f};

    for (int c = cb_; c < ce_; ++c) {
        int j0 = c * 64;
        int d0 = 1008 + j0 - i0w;
        bool interior = (j0 + 63 <= i0w + M_) && (d0 >= 0) && (d0 + 79 <= 2047);
        // ---- AC: 4 column-subtiles of 16 ----
        f32x4 ac[4];
        #pragma unroll
        for (int su = 0; su < 4; ++su) {
            const ushort* krow = kp + (size_t)(j0 + su * 16 + jl) * 64;
            bf16x8 k0 = *(const bf16x8*)(krow + quad * 8);
            bf16x8 k1 = *(const bf16x8*)(krow + 32 + quad * 8);
            f32x4 t = MFMA16(quA[0], k0, z);
            ac[su] = MFMA16(quA[1], k1, t);
        }
        // ---- BD windows: 5 n-tiles covering r-rows d0 .. d0+79 ----
        f32x4 bt[5];
        if (interior) {
            #pragma unroll
            for (int nt = 0; nt < 5; ++nt) {
                const ushort* rrow = rp + (size_t)(d0 + nt * 16 + jl) * 64;
                bf16x8 r0 = *(const bf16x8*)(rrow + quad * 8);
                bf16x8 r1 = *(const bf16x8*)(rrow + 32 + quad * 8);
                f32x4 t = MFMA16(qvA[0], r0, z);
                bt[nt] = MFMA16(qvA[1], r1, t);
            }
            // ---- diagonal extraction, exp2, NT store; no mask ----
            #pragma unroll
            for (int r = 0; r < 4; ++r) {
                int ii = quad * 4 + r;
                int src = (quad << 4) | ((jl + 15 - ii) & 15);
                float bs[5];
                #pragma unroll
                for (int nt = 0; nt < 5; ++nt) bs[nt] = __shfl(bt[nt][r], src);
                bool hi = (jl > ii);
                ushort* prow = AMw + ((size_t)(irow + r) * 32 + bh) * 2048 + j0 + jl;
                #pragma unroll
                for (int su = 0; su < 4; ++su) {
                    float bd = hi ? bs[su + 1] : bs[su];
                    float p = exp2f(fminf((ac[su][r] + bd) * SCALE2_, 86.f));
                    lsum[r] += p;
                    __builtin_nontemporal_store(f2bf_fast(p), prow + su * 16);
                }
            }
        } else {
            #pragma unroll
            for (int nt = 0; nt < 5; ++nt) {
                int rr = d0 + nt * 16 + jl;
                rr = min(max(rr, 0), 2047);
                const ushort* rrow = rp + (size_t)rr * 64;
                bf16x8 r0 = *(const bf16x8*)(rrow + quad * 8);
                bf16x8 r1 = *(const bf16x8*)(rrow + 32 + quad * 8);
                f32x4 t = MFMA16(qvA[0], r0, z);
                bt[nt] = MFMA16(qvA[1], r1, t);
            }
            #pragma unroll
            for (int r = 0; r < 4; ++r) {
                int ii = quad * 4 + r;
                int src = (quad << 4) | ((jl + 15 - ii) & 15);
                float bs[5];
                #pragma unroll
                for (int nt = 0; nt < 5; ++nt) bs[nt] = __shfl(bt[nt][r], src);
                bool hi = (jl > ii);
                ushort* prow = AMw + ((size_t)(irow + r) * 32 + bh) * 2048 + j0 + jl;
                #pragma unroll
                for (int su = 0; su < 4; ++su) {
                    float bd = hi ? bs[su + 1] : bs[su];
                    float sv = (ac[su][r] + bd) * SCALE2_;
                    int j = j0 + su * 16 + jl;
                    float p = (j <= irow + r + M_) ? exp2f(fminf(sv, 86.f)) : 0.f;
                    lsum[r] += p;
                    __builtin_nontemporal_store(f2bf_fast(p), prow + su * 16);
                }
            }
        }
    }

    // ---- epilogue: l partial sums ----
    #pragma unroll
    for (int r = 0; r < 4; ++r) {
        #pragma unroll
        for (int off = 1; off < 16; off <<= 1) lsum[r] += __shfl_xor(lsum[r], off);
        if (jl == 0) atomicAdd(&lpart[(size_t)bh * 1024 + irow + r], lsum[r]);
    }
}

// ---------------------------------------------------------------------------
// PV GEMM: O[bh][i][d] = (1/l_i) * sum_j P[i][bh][j] * V[bh][j][d].
// 64x64 tiles; K bounded by causal region 64*(17+mt). Folds o_combine.
// ---------------------------------------------------------------------------
__global__ __launch_bounds__(256) void pv_gemm(
    const ushort* __restrict__ P, const ushort* __restrict__ Vt,
    const float* __restrict__ lpart,
    ushort* __restrict__ OvecB, float* __restrict__ linvs)
{
    __shared__ ushort Al[64][40];
    __shared__ ushort Bl[64][40];
    int tid = threadIdx.x;
    int lin  = blockIdx.x;             // 512
    int xcd  = lin & 7;
    int rest = lin >> 3;               // 0..63
    int bh   = (xcd << 2) | (rest & 3);
    int mt   = rest >> 2;              // 0..15
    int M0   = mt * 64;
    int wid = tid >> 6, lane = tid & 63, quad = lane >> 4, jl = lane & 15;
    int m0w = (wid >> 1) * 32, n0w = (wid & 1) * 32;
    int sr = tid >> 2, sc = (tid & 3) * 8;

    const ushort* Bp = Vt + (size_t)bh * 64 * 2048;
    int kend = (17 + mt) * 64;

    f32x4 acc[2][2];
    #pragma unroll
    for (int i = 0; i < 2; ++i)
        #pragma unroll
        for (int j = 0; j < 2; ++j) acc[i][j] = (f32x4){0.f, 0.f, 0.f, 0.f};

    for (int k0 = 0; k0 < kend; k0 += 32) {
        *(u16x8v*)&Al[sr][sc] =
            *(const u16x8v*)(P + ((size_t)(M0 + sr) * 32 + bh) * 2048 + k0 + sc);
        *(u16x8v*)&Bl[sr][sc] = *(const u16x8v*)(Bp + (size_t)sr * 2048 + k0 + sc);
        __syncthreads();
        bf16x8 a0 = *(const bf16x8*)&Al[m0w + jl][quad * 8];
        bf16x8 a1 = *(const bf16x8*)&Al[m0w + 16 + jl][quad * 8];
        bf16x8 b0 = *(const bf16x8*)&Bl[n0w + jl][quad * 8];
        bf16x8 b1 = *(const bf16x8*)&Bl[n0w + 16 + jl][quad * 8];
        acc[0][0] = MFMA16(a0, b0, acc[0][0]);
        acc[0][1] = MFMA16(a0, b1, acc[0][1]);
        acc[1][0] = MFMA16(a1, b0, acc[1][0]);
        acc[1][1] = MFMA16(a1, b1, acc[1][1]);
        __syncthreads();
    }

    int b = bh >> 4, h = bh & 15;
    #pragma unroll
    for (int ms = 0; ms < 2; ++ms)
        #pragma unroll
        for (int r = 0; r < 4; ++r) {
            int gi = M0 + m0w + 16 * ms + quad * 4 + r;
            float linv = 1.f / lpart[(size_t)bh * 1024 + gi];
            #pragma unroll
            for (int ns = 0; ns < 2; ++ns) {
                int gd = n0w + 16 * ns + jl;
                OvecB[(size_t)(gi * 2 + b) * 1024 + h * 64 + gd] =
                    f2bf(acc[ms][ns][r] * linv);
            }
            if (n0w == 0 && jl == 0)
                linvs[(size_t)gi * 32 + bh] = linv * 0.03125f;
        }
}

// ---------------------------------------------------------------------------
// Fused tail: blocks [0,512) = output projection + residual (64x64 tiles);
// blocks [512,1536) = am_reduce row i = lin-512 (contiguous 128 KB stream).
// Both depend only on pv_gemm/attn_score outputs -> safe to co-schedule.
// ---------------------------------------------------------------------------
__global__ __launch_bounds__(256) void tail_fused(
    const ushort* __restrict__ A, const ushort* __restrict__ Wt,
    const float* __restrict__ resid, float* __restrict__ outF,
    const ushort* __restrict__ AMw, const float* __restrict__ linvs,
    float* __restrict__ AM)
{
    __shared__ ushort Al[64][40];
    __shared__ ushort Bl[64][40];
    int tid = threadIdx.x;
    int lin = blockIdx.x;
    if (lin >= 512) {
        // ---- am_reduce ----
        __shared__ float lv[32];
        int i = lin - 512;
        if (tid < 32) lv[tid] = linvs[(size_t)i * 32 + tid];
        __syncthreads();
        int j0 = tid * 8;
        int jmax = i + M_;
        float acc[8];
        #pragma unroll
        for (int e = 0; e < 8; ++e) acc[e] = 0.f;
        if (j0 <= jmax) {
            const ushort* base = AMw + (size_t)i * 65536;
            for (int p = 0; p < 32; ++p) {
                float l = lv[p];
                u16x8v v = __builtin_nontemporal_load(
                    (const u16x8v*)(base + (size_t)p * 2048 + j0));
                #pragma unroll
                for (int e = 0; e < 8; ++e) acc[e] += bf2f(v[e]) * l;
            }
        }
        float4 o0, o1;
        o0.x = (j0 + 0 <= jmax) ? acc[0] : 0.f;
        o0.y = (j0 + 1 <= jmax) ? acc[1] : 0.f;
        o0.z = (j0 + 2 <= jmax) ? acc[2] : 0.f;
        o0.w = (j0 + 3 <= jmax) ? acc[3] : 0.f;
        o1.x = (j0 + 4 <= jmax) ? acc[4] : 0.f;
        o1.y = (j0 + 5 <= jmax) ? acc[5] : 0.f;
        o1.z = (j0 + 6 <= jmax) ? acc[6] : 0.f;
        o1.w = (j0 + 7 <= jmax) ? acc[7] : 0.f;
        *(float4*)(AM + (size_t)i * 2048 + j0) = o0;
        *(float4*)(AM + (size_t)i * 2048 + j0 + 4) = o1;
        return;
    }
    // ---- gemm_o ----
    int M0 = (lin & 31) * 64, N0 = (lin >> 5) * 64;
    int wid = tid >> 6, lane = tid & 63, quad = lane >> 4, jl = lane & 15;
    int m0w = (wid >> 1) * 32, n0w = (wid & 1) * 32;
    int sr = tid >> 2, sc = (tid & 3) * 8;

    f32x4 acc[2][2];
    #pragma unroll
    for (int i = 0; i < 2; ++i)
        #pragma unroll
        for (int j = 0; j < 2; ++j) acc[i][j] = (f32x4){0.f, 0.f, 0.f, 0.f};

    for (int k0 = 0; k0 < 1024; k0 += 32) {
        *(u16x8v*)&Al[sr][sc] = *(const u16x8v*)(A  + (size_t)(M0 + sr) * 1024 + k0 + sc);
        *(u16x8v*)&Bl[sr][sc] = *(const u16x8v*)(Wt + (size_t)(N0 + sr) * 1024 + k0 + sc);
        __syncthreads();
        bf16x8 a0 = *(const bf16x8*)&Al[m0w + jl][quad * 8];
        bf16x8 a1 = *(const bf16x8*)&Al[m0w + 16 + jl][quad * 8];
        bf16x8 b0 = *(const bf16x8*)&Bl[n0w + jl][quad * 8];
        bf16x8 b1 = *(const bf16x8*)&Bl[n0w + 16 + jl][quad * 8];
        acc[0][0] = MFMA16(a0, b0, acc[0][0]);
        acc[0][1] = MFMA16(a0, b1, acc[0][1]);
        acc[1][0] = MFMA16(a1, b0, acc[1][0]);
        acc[1][1] = MFMA16(a1, b1, acc[1][1]);
        __syncthreads();
    }

    #pragma unroll
    for (int ms = 0; ms < 2; ++ms)
        #pragma unroll
        for (int ns = 0; ns < 2; ++ns)
            #pragma unroll
            for (int r = 0; r < 4; ++r) {
                int gm = M0 + m0w + 16 * ms + quad * 4 + r;
                int gn = N0 + n0w + 16 * ns + jl;
                outF[(size_t)gm * 1024 + gn] =
                    acc[ms][ns][r] + resid[(size_t)gm * 1024 + gn];
            }
}

// ---------------------------------------------------------------------------
// LayerNorm over D=1024, one block per row
// ---------------------------------------------------------------------------
__global__ __launch_bounds__(256) void ln_kernel(
    const float* __restrict__ hbuf,
    const float* __restrict__ gamma, const float* __restrict__ beta,
    float* __restrict__ out)
{
    __shared__ float rs[4], rss[4];
    int row = blockIdx.x;
    int tid = threadIdx.x;
    const float* hp = hbuf + (size_t)row * 1024;
    float4 h4 = *(const float4*)(hp + (tid << 2));
    float s = h4.x + h4.y + h4.z + h4.w;
    float ss = h4.x * h4.x + h4.y * h4.y + h4.z * h4.z + h4.w * h4.w;
    #pragma unroll
    for (int o = 32; o > 0; o >>= 1) {
        s  += __shfl_down(s, o);
        ss += __shfl_down(ss, o);
    }
    if ((tid & 63) == 0) { rs[tid >> 6] = s; rss[tid >> 6] = ss; }
    __syncthreads();
    float tot  = rs[0] + rs[1] + rs[2] + rs[3];
    float tots = rss[0] + rss[1] + rss[2] + rss[3];
    float mu = tot * (1.f / 1024.f);
    float var = tots * (1.f / 1024.f) - mu * mu;
    float rstd = rsqrtf(var + 1e-5f);
    float4 g4 = *(const float4*)(gamma + (tid << 2));
    float4 b4 = *(const float4*)(beta + (tid << 2));
    float4 o4;
    o4.x = (h4.x - mu) * rstd * g4.x + b4.x;
    o4.y = (h4.y - mu) * rstd * g4.y + b4.y;
    o4.z = (h4.z - mu) * rstd * g4.z + b4.z;
    o4.w = (h4.w - mu) * rstd * g4.w + b4.w;
    *(float4*)(out + (size_t)row * 1024 + (tid << 2)) = o4;
}

extern "C" void kernel_launch(void* const* d_in, const int* in_sizes, int n_in,
                              void* d_out, int out_size, void* d_ws, size_t ws_size,
                              hipStream_t stream) {
    const float* x       = (const float*)d_in[0];
    const float* pos_emb = (const float*)d_in[1];
    const float* memory  = (const float*)d_in[2];
    const float* bu      = (const float*)d_in[3];
    const float* bv      = (const float*)d_in[4];
    const float* Wq      = (const float*)d_in[6];
    const float* Wkv     = (const float*)d_in[7];
    const float* Wrel    = (const float*)d_in[8];
    const float* Wo      = (const float*)d_in[9];
    const float* gamma   = (const float*)d_in[10];
    const float* beta    = (const float*)d_in[11];

    float* out = (float*)d_out;
    float* AM  = out + (size_t)2097152;       // attn_matrix [L][T]

    ushort* cb    = (ushort*)d_ws;            // [4096][1024]
    ushort* pb    = cb    + 4194304;          // [4096][1024]
    ushort* Wqt   = pb    + 4194304;          // [1024][1024]
    ushort* Wkvt  = Wqt   + 1048576;          // [2048][1024]
    ushort* Wrelt = Wkvt  + 2097152;          // [1024][1024]
    ushort* Wot   = Wrelt + 1048576;          // [1024][1024]
    ushort* quB   = Wot   + 1048576;          // [32][1024][64]
    ushort* qvB   = quB   + 2097152;
    ushort* kbB   = qvB   + 2097152;          // [32][2048][64]
    ushort* VtB   = kbB   + 4194304;          // [32][64][2048]
    ushort* rbB   = VtB   + 4194304;          // [32][2048][64]
    ushort* OvecB = rbB   + 4194304;          // [2048][1024]
    float*  hbuf  = (float*)(OvecB + 2097152);// [2048][1024] fp32
    float*  lpart = hbuf  + 2097152;          // [32][1024] fp32
    float*  linvs = lpart + 32768;            // [1024][32] fp32
    ushort* AMw   = (ushort*)(linvs + 32768); // [1024][32][2048] bf16 (128 MB)

    dim3 blk(256);
    // fused converts + weight transposes + lpart clear
    prep<<<9248, blk, 0, stream>>>(memory, x, pos_emb, Wq, Wkv, Wrel, Wo,
                                   cb, pb, Wqt, Wkvt, Wrelt, Wot, lpart);
    // all projections in one 128x128-tile launch (896 blocks)
    proj_all<<<896, blk, 0, stream>>>(cb, pb, Wqt, Wkvt, Wrelt, bu, bv,
                                      quB, qvB, kbB, VtB, rbB);
    // scores -> planes (fence-free, LDS-free, interior fast path)
    attn_score<<<dim3(2048), blk, 0, stream>>>(quB, qvB, kbB, rbB, lpart, AMw);
    // PV as causal-K GEMM; folds o_combine
    pv_gemm<<<dim3(512), blk, 0, stream>>>(AMw, VtB, lpart, OvecB, linvs);
    // fused output projection + attn_matrix reduction
    tail_fused<<<dim3(1536), blk, 0, stream>>>(OvecB, Wot, x, hbuf,
                                               AMw, linvs, AM);
    // layernorm
    ln_kernel<<<2048, blk, 0, stream>>>(hbuf, gamma, beta, out);
}